// Round 1
// baseline (2570.977 us; speedup 1.0000x reference)
//
#include <hip/hip_runtime.h>
#include <hip/hip_bf16.h>

// ---- problem constants ----
constexpr int B   = 8;
constexpr int CIN = 66;     // cnn_feature channels
constexpr int H   = 128, W = 128;
constexpr int C1  = 256;    // proj conv1 out
constexpr int C2  = 64;     // proj conv2 out
constexpr int NP  = 128;    // polys
constexpr int V   = 128;    // vertices
constexpr int SD  = 128;    // snake state dim
constexpr int FD  = 66;     // snake feature dim (64 feat + 2 coords)
constexpr int NRES = 7;
constexpr int NSTATE = NRES + 1;      // 8
constexpr int SCH = SD * NSTATE;      // 1024
constexpr float RO = 4.0f;

// ===================== K1: 3x3 conv + ReLU -> bf16 =====================
// grid (32 ocg, 64 ypair, 8 b), block 256 (= 2 rows x 128 cols), 8 oc per block
__global__ __launch_bounds__(256) void k_conv3x3_relu(
    const float* __restrict__ x, const float* __restrict__ w,
    const float* __restrict__ bias, __hip_bfloat16* __restrict__ out)
{
    const int tid  = threadIdx.x;
    const int xcol = tid & 127;
    const int yrow = tid >> 7;
    const int ocb  = blockIdx.x * 8;
    const int y    = blockIdx.y * 2 + yrow;
    const int b    = blockIdx.z;

    __shared__ float wl[8 * CIN * 9];
    for (int i = tid; i < 8 * CIN * 9; i += 256) wl[i] = w[ocb * CIN * 9 + i];
    __syncthreads();

    int   roff[3], coff[3];
    float rokf[3], cokf[3];
#pragma unroll
    for (int t = 0; t < 3; ++t) {
        int yy = y + t - 1;
        rokf[t] = (yy >= 0 && yy < H) ? 1.f : 0.f;
        roff[t] = (yy < 0 ? 0 : (yy > H - 1 ? H - 1 : yy)) * W;
        int xx = xcol + t - 1;
        cokf[t] = (xx >= 0 && xx < W) ? 1.f : 0.f;
        coff[t] = (xx < 0 ? 0 : (xx > W - 1 ? W - 1 : xx));
    }
    float mk[9];
#pragma unroll
    for (int ky = 0; ky < 3; ++ky)
#pragma unroll
        for (int kx = 0; kx < 3; ++kx) mk[ky * 3 + kx] = rokf[ky] * cokf[kx];

    float acc[8];
#pragma unroll
    for (int i = 0; i < 8; ++i) acc[i] = 0.f;

    const float* xb = x + (size_t)b * CIN * H * W;
    for (int ic = 0; ic < CIN; ++ic) {
        const float* xp = xb + (size_t)ic * H * W;
        float xv[9];
#pragma unroll
        for (int ky = 0; ky < 3; ++ky)
#pragma unroll
            for (int kx = 0; kx < 3; ++kx)
                xv[ky * 3 + kx] = xp[roff[ky] + coff[kx]] * mk[ky * 3 + kx];
#pragma unroll
        for (int i = 0; i < 8; ++i) {
            const float* wp = &wl[(i * CIN + ic) * 9];
#pragma unroll
            for (int k = 0; k < 9; ++k) acc[i] += wp[k] * xv[k];
        }
    }
#pragma unroll
    for (int i = 0; i < 8; ++i) {
        float vv = acc[i] + bias[ocb + i];
        vv = vv > 0.f ? vv : 0.f;
        out[(((size_t)b * C1 + ocb + i) * H + y) * W + xcol] = __float2bfloat16(vv);
    }
}

// ===================== K2: 1x1 conv (256 -> 64) =====================
// grid 512, block 256: each thread one pixel, all 64 outputs in regs
__global__ __launch_bounds__(256) void k_conv1x1(
    const __hip_bfloat16* __restrict__ xin, const float* __restrict__ w2,
    const float* __restrict__ b2, float* __restrict__ out)
{
    const int tid = threadIdx.x;
    const int pix = blockIdx.x * 256 + tid;
    const int b   = pix >> 14;
    const int sp  = pix & 16383;

    __shared__ float wsh[64 * 64];  // [c][o]
    float acc[64];
#pragma unroll
    for (int o = 0; o < 64; ++o) acc[o] = 0.f;

    for (int cc = 0; cc < 4; ++cc) {
        __syncthreads();
        for (int i = tid; i < 64 * 64; i += 256) {
            int c = i >> 6, o = i & 63;
            wsh[i] = w2[o * 256 + cc * 64 + c];
        }
        __syncthreads();
        const __hip_bfloat16* xp = xin + ((size_t)(b * 256 + cc * 64) * 16384) + sp;
        for (int c = 0; c < 64; ++c) {
            float xv = __bfloat162float(xp[(size_t)c * 16384]);
#pragma unroll
            for (int o = 0; o < 64; ++o) acc[o] += wsh[c * 64 + o] * xv;
        }
    }
    float* op = out + (size_t)b * 64 * 16384 + sp;
#pragma unroll
    for (int o = 0; o < 64; ++o) op[(size_t)o * 16384] = acc[o] + b2[o];
}

// ===================== K3: bilinear sample + coords -> X0 =====================
// grid (128, 4), block 128
__global__ __launch_bounds__(128) void k_sample(
    const float* __restrict__ feat2, const float* __restrict__ ipoly,
    const float* __restrict__ cpoly, const int* __restrict__ ind,
    float* __restrict__ X0)
{
    const int v  = threadIdx.x;
    const int p  = blockIdx.x;
    const int cg = blockIdx.y;

    float px = ipoly[(p * V + v) * 2 + 0];
    float py = ipoly[(p * V + v) * 2 + 1];
    float ix = px - 0.5f, iy = py - 0.5f;
    float x0f = floorf(ix), y0f = floorf(iy);
    float wx = ix - x0f, wy = iy - y0f;
    int x0 = (int)x0f, y0 = (int)y0f;
    int b  = ind[p];

    int   xsv[2] = {x0, x0 + 1}, ysv[2] = {y0, y0 + 1};
    float wxs[2] = {1.f - wx, wx}, wys[2] = {1.f - wy, wy};
    float cw[4]; int cbase[4];
#pragma unroll
    for (int jy = 0; jy < 2; ++jy)
#pragma unroll
        for (int jx = 0; jx < 2; ++jx) {
            int xi = xsv[jx], yi = ysv[jy];
            bool ok = (xi >= 0) && (xi < W) && (yi >= 0) && (yi < H);
            int xc = min(max(xi, 0), W - 1);
            int yc = min(max(yi, 0), H - 1);
            cw[jy * 2 + jx]    = wys[jy] * wxs[jx] * (ok ? 1.f : 0.f);
            cbase[jy * 2 + jx] = yc * W + xc;
        }

    const float* fb = feat2 + (size_t)b * C2 * H * W + (size_t)cg * 16 * H * W;
    float* xo = X0 + ((size_t)p * FD + cg * 16) * V + v;
    for (int c = 0; c < 16; ++c) {
        const float* fc = fb + (size_t)c * H * W;
        float val = fc[cbase[0]] * cw[0] + fc[cbase[1]] * cw[1] +
                    fc[cbase[2]] * cw[2] + fc[cbase[3]] * cw[3];
        xo[(size_t)c * V] = val;
    }
    if (cg == 0) {
        X0[((size_t)p * FD + 64) * V + v] = cpoly[(p * V + v) * 2 + 0] * RO;
        X0[((size_t)p * FD + 65) * V + v] = cpoly[(p * V + v) * 2 + 1] * RO;
    }
}

// ===================== K4: circular dilated conv + relu + bn (+res) =====================
// grid (128 p, 4 ocg), block 256 = 32 oc x 8 vgroups(16 v each)
template <int DIL>
__global__ __launch_bounds__(256) void k_snake(
    const float* __restrict__ xin, int xin_pstride, int Cin,
    const float* __restrict__ w, const float* __restrict__ bias,
    const float* __restrict__ gamma, const float* __restrict__ beta,
    const float* __restrict__ resin,   // nullable (pstride SCH*V)
    float* __restrict__ out)           // states + Lout*SD*V (pstride SCH*V)
{
    constexpr int W2  = V + 8 * DIL;
    constexpr int WIN = 16 + 8 * DIL;
    const int tid = threadIdx.x;
    const int ocl = tid & 31;
    const int vg  = tid >> 5;
    const int v0  = vg * 16;
    const int p   = blockIdx.x;
    const int oc  = blockIdx.y * 32 + ocl;

    __shared__ float xs[64 * W2];
    float acc[16];
#pragma unroll
    for (int i = 0; i < 16; ++i) acc[i] = 0.f;

    const float* xb = xin + (size_t)p * xin_pstride;
    for (int icc = 0; icc < Cin; icc += 64) {
        int csz = min(64, Cin - icc);
        __syncthreads();
        for (int i = tid; i < csz * W2; i += 256) {
            int ic = i / W2, j = i % W2;
            xs[i] = xb[(size_t)(icc + ic) * V + ((j + V - 4 * DIL) & (V - 1))];
        }
        __syncthreads();
        const float* wb = w + ((size_t)oc * Cin + icc) * 9;
        for (int ic = 0; ic < csz; ++ic) {
            float wk[9];
#pragma unroll
            for (int k = 0; k < 9; ++k) wk[k] = wb[ic * 9 + k];
            float xw[WIN];
#pragma unroll
            for (int t = 0; t < WIN; ++t) xw[t] = xs[ic * W2 + v0 + t];
#pragma unroll
            for (int k = 0; k < 9; ++k)
#pragma unroll
                for (int vv = 0; vv < 16; ++vv)
                    acc[vv] += wk[k] * xw[vv + k * DIL];
        }
    }

    float bb = bias[oc], gg = gamma[oc], bt = beta[oc];
    float* op = out + (size_t)p * (SCH * V) + (size_t)oc * V + v0;
    const float* rp = resin ? (resin + (size_t)p * (SCH * V) + (size_t)oc * V + v0) : nullptr;
#pragma unroll
    for (int vv = 0; vv < 16; ++vv) {
        float yv = acc[vv] + bb;
        yv = yv > 0.f ? yv : 0.f;
        yv = yv * gg + bt;
        if (rp) yv += rp[vv];
        op[vv] = yv;
    }
}

// ===================== K5: generic per-vertex 1x1 conv =====================
// grid (128 p, O/64), block 256 = 8 othreads x 32 vthreads; 8 o x 4 v per thread
__global__ __launch_bounds__(256) void k_vconv(
    const float* __restrict__ xin, int pstride, int C,
    const float* __restrict__ w, int wstride,
    const float* __restrict__ bias,    // nullable per-o
    const float* __restrict__ pbias,   // nullable per (p,o)
    int O, int relu,
    float* __restrict__ out)
{
    const int tid = threadIdx.x;
    const int ot  = tid >> 5;
    const int vt  = tid & 31;
    const int v4  = vt * 4;
    const int p   = blockIdx.x;
    const int ob  = blockIdx.y * 64;

    __shared__ __align__(16) float xsh[64 * V];
    __shared__ float wsh[64 * 64];   // [c][o]
    float acc[8][4];
#pragma unroll
    for (int o = 0; o < 8; ++o)
#pragma unroll
        for (int j = 0; j < 4; ++j) acc[o][j] = 0.f;

    const float* xb = xin + (size_t)p * pstride;
    for (int cc = 0; cc < C; cc += 64) {
        __syncthreads();
        for (int i = tid; i < 64 * V; i += 256) xsh[i] = xb[(size_t)cc * V + i];
        for (int i = tid; i < 64 * 64; i += 256) {
            int c = i >> 6, o = i & 63;
            wsh[i] = w[(size_t)(ob + o) * wstride + cc + c];
        }
        __syncthreads();
        for (int c = 0; c < 64; ++c) {
            float4 xv = *(const float4*)&xsh[c * V + v4];
#pragma unroll
            for (int o = 0; o < 8; ++o) {
                float wv = wsh[c * 64 + ot * 8 + o];
                acc[o][0] += wv * xv.x;
                acc[o][1] += wv * xv.y;
                acc[o][2] += wv * xv.z;
                acc[o][3] += wv * xv.w;
            }
        }
    }
#pragma unroll
    for (int o = 0; o < 8; ++o) {
        int og = ob + ot * 8 + o;
        float bb = (bias ? bias[og] : 0.f) + (pbias ? pbias[(size_t)p * O + og] : 0.f);
        float4 r;
        r.x = acc[o][0] + bb; r.y = acc[o][1] + bb;
        r.z = acc[o][2] + bb; r.w = acc[o][3] + bb;
        if (relu) {
            r.x = r.x > 0.f ? r.x : 0.f; r.y = r.y > 0.f ? r.y : 0.f;
            r.z = r.z > 0.f ? r.z : 0.f; r.w = r.w > 0.f ? r.w : 0.f;
        }
        *(float4*)&out[(size_t)p * O * V + (size_t)og * V + v4] = r;
    }
}

// ===================== K6: max over vertices =====================
__global__ __launch_bounds__(256) void k_gmax(const float* __restrict__ fused,
                                              float* __restrict__ g)
{
    int p = blockIdx.x, o = threadIdx.x;
    const float4* fp = (const float4*)(fused + ((size_t)p * 256 + o) * V);
    float m = -3.4e38f;
    for (int i = 0; i < V / 4; ++i) {
        float4 t = fp[i];
        m = fmaxf(m, fmaxf(fmaxf(t.x, t.y), fmaxf(t.z, t.w)));
    }
    g[(size_t)p * 256 + o] = m;
}

// ===================== K7: gc[p][o] = pb1[o] + pw1[o,0:256] . g[p] =====================
__global__ __launch_bounds__(256) void k_gc(const float* __restrict__ g,
                                            const float* __restrict__ pw1,
                                            const float* __restrict__ pb1,
                                            float* __restrict__ gc)
{
    int p = blockIdx.x, o = threadIdx.x;
    __shared__ float gl[256];
    gl[o] = g[(size_t)p * 256 + o];
    __syncthreads();
    float a = pb1[o];
    const float* wr = pw1 + (size_t)o * 1280;
    for (int c = 0; c < 256; ++c) a += wr[c] * gl[c];
    gc[(size_t)p * 256 + o] = a;
}

// ===================== K8: final pw3 + compose output =====================
__global__ __launch_bounds__(128) void k_final(const float* __restrict__ h2,
                                               const float* __restrict__ pw3,
                                               const float* __restrict__ pb3,
                                               const float* __restrict__ ipoly,
                                               float* __restrict__ outp)
{
    int p = blockIdx.x, v = threadIdx.x;
    __shared__ float w3[128];
    w3[v] = pw3[v];
    __syncthreads();
    float a0 = pb3[0], a1 = pb3[1];
    const float* hp = h2 + (size_t)p * 64 * V + v;
    for (int c = 0; c < 64; ++c) {
        float hv = hp[(size_t)c * V];
        a0 += w3[c] * hv;
        a1 += w3[64 + c] * hv;
    }
    int idx = (p * V + v) * 2;
    outp[idx]     = ipoly[idx] * RO + a0;
    outp[idx + 1] = ipoly[idx + 1] * RO + a1;
}

// ===================== host =====================
extern "C" void kernel_launch(void* const* d_in, const int* in_sizes, int n_in,
                              void* d_out, int out_size, void* d_ws, size_t ws_size,
                              hipStream_t stream)
{
    const float* cnn   = (const float*)d_in[0];
    const float* ipoly = (const float*)d_in[1];
    const float* cpoly = (const float*)d_in[2];
    const int*   ind   = (const int*)d_in[3];
    const float* pw1c  = (const float*)d_in[4];  // proj_w1
    const float* pb1c  = (const float*)d_in[5];
    const float* pw2c  = (const float*)d_in[6];  // proj_w2
    const float* pb2c  = (const float*)d_in[7];
    const float* hw    = (const float*)d_in[8];
    const float* hb    = (const float*)d_in[9];
    const float* hg    = (const float*)d_in[10];
    const float* hbt   = (const float*)d_in[11];
    const float* rw    = (const float*)d_in[12];
    const float* rb    = (const float*)d_in[13];
    const float* rg    = (const float*)d_in[14];
    const float* rbt   = (const float*)d_in[15];
    const float* fw    = (const float*)d_in[16];
    const float* fb    = (const float*)d_in[17];
    const float* ppw1  = (const float*)d_in[18];
    const float* ppb1  = (const float*)d_in[19];
    const float* ppw2  = (const float*)d_in[20];
    const float* ppb2  = (const float*)d_in[21];
    const float* ppw3  = (const float*)d_in[22];
    const float* ppb3  = (const float*)d_in[23];
    float* outp = (float*)d_out;

    char* ws = (char*)d_ws;
    // layout (bytes):
    //   [0, 67108864)            feat1 (bf16)  / later states (f32) -- aliased
    //   [67108864, 100663296)    feat2 (f32)   / later fused(=h1), g, gc, h2
    //   [100663296, +4325376)    X0
    __hip_bfloat16* feat1 = (__hip_bfloat16*)(ws);
    float* states = (float*)(ws);
    float* feat2  = (float*)(ws + 67108864);
    float* fused  = (float*)(ws + 67108864);            // alias over dead feat2
    float* h1     = fused;
    float* gbuf   = (float*)(ws + 67108864 + 16777216);
    float* gcbuf  = (float*)(ws + 67108864 + 16777216 + 131072);
    float* h2     = (float*)(ws + 67108864 + 16777216 + 262144);
    float* X0     = (float*)(ws + 100663296);

    // 1) 3x3 conv + relu -> feat1 (bf16)
    k_conv3x3_relu<<<dim3(32, 64, 8), 256, 0, stream>>>(cnn, pw1c, pb1c, feat1);
    // 2) 1x1 conv -> feat2
    k_conv1x1<<<dim3(512), 256, 0, stream>>>(feat1, pw2c, pb2c, feat2);
    // 3) bilinear sample + coords -> X0
    k_sample<<<dim3(NP, 4), 128, 0, stream>>>(feat2, ipoly, cpoly, ind, X0);
    // 4) head conv (d=1, Cin=66) -> states block 0
    k_snake<1><<<dim3(NP, 4), 256, 0, stream>>>(X0, FD * V, FD, hw, hb, hg, hbt,
                                                nullptr, states);
    // 5..11) residual dilated convs
    const int dil[NRES] = {1, 1, 1, 2, 2, 4, 4};
    for (int i = 0; i < NRES; ++i) {
        const float* xin = states + (size_t)i * SD * V;
        float* yout      = states + (size_t)(i + 1) * SD * V;
        const float* wi  = rw + (size_t)i * SD * SD * 9;
        if (dil[i] == 1)
            k_snake<1><<<dim3(NP, 4), 256, 0, stream>>>(xin, SCH * V, SD, wi,
                rb + i * SD, rg + i * SD, rbt + i * SD, xin, yout);
        else if (dil[i] == 2)
            k_snake<2><<<dim3(NP, 4), 256, 0, stream>>>(xin, SCH * V, SD, wi,
                rb + i * SD, rg + i * SD, rbt + i * SD, xin, yout);
        else
            k_snake<4><<<dim3(NP, 4), 256, 0, stream>>>(xin, SCH * V, SD, wi,
                rb + i * SD, rg + i * SD, rbt + i * SD, xin, yout);
    }
    // 12) fused 1x1 over state -> fused (p,256,V)
    k_vconv<<<dim3(NP, 4), 256, 0, stream>>>(states, SCH * V, SCH, fw, SCH,
                                             fb, nullptr, 256, 0, fused);
    // 13) g = max over vertices
    k_gmax<<<dim3(NP), 256, 0, stream>>>(fused, gbuf);
    // 14) gc = pb1 + pw1[:, :256] @ g
    k_gc<<<dim3(NP), 256, 0, stream>>>(gbuf, ppw1, ppb1, gcbuf);
    // 15) h1 = relu(pw1[:, 256:] @ state + gc)   (h1 aliases fused, consumed already)
    k_vconv<<<dim3(NP, 4), 256, 0, stream>>>(states, SCH * V, SCH, ppw1 + 256, 1280,
                                             nullptr, gcbuf, 256, 1, h1);
    // 16) h2 = relu(pw2 @ h1 + pb2)
    k_vconv<<<dim3(NP, 1), 256, 0, stream>>>(h1, 256 * V, 256, ppw2, 256,
                                             ppb2, nullptr, 64, 1, h2);
    // 17) final: out = ipoly*RO + pw3 @ h2 + pb3
    k_final<<<dim3(NP), 128, 0, stream>>>(h2, ppw3, ppb3, ipoly, outp);
}

// Round 2
// 1567.720 us; speedup vs baseline: 1.6399x; 1.6399x over previous
//
#include <hip/hip_runtime.h>
#include <hip/hip_bf16.h>

// ---- problem constants ----
constexpr int B   = 8;
constexpr int CIN = 66;     // cnn_feature channels
constexpr int H   = 128, W = 128;
constexpr int C1  = 256;    // proj conv1 out
constexpr int C2  = 64;     // proj conv2 out
constexpr int NP  = 128;    // polys
constexpr int V   = 128;    // vertices
constexpr int SD  = 128;    // snake state dim
constexpr int FD  = 66;     // snake feature dim (64 feat + 2 coords)
constexpr int NRES = 7;
constexpr int NSTATE = NRES + 1;      // 8
constexpr int SCH = SD * NSTATE;      // 1024
constexpr float RO = 4.0f;

typedef __bf16 bf16x8 __attribute__((ext_vector_type(8)));
typedef float  f32x4  __attribute__((ext_vector_type(4)));

struct alignas(8) bh4 { __hip_bfloat16 v[4]; };

// ===================== K0a: pack x -> channel-last bf16 with borders =====================
// xp: [8][130][130][72] bf16, zero spatial border (1px) and zero ic pad (66->72)
__global__ __launch_bounds__(256) void k_pack_x(const float* __restrict__ x,
                                                __hip_bfloat16* __restrict__ xp)
{
    const int bi  = blockIdx.x;          // 8*130
    const int b   = bi / 130;
    const int yp  = bi % 130;
    const int tid = threadIdx.x;
    const int y   = yp - 1;
    const bool interior = (y >= 0 && y < H);

    __shared__ float xs[CIN * W];
    if (interior) {
        for (int i = tid; i < CIN * W; i += 256)
            xs[i] = x[((size_t)b * CIN + (i >> 7)) * (H * W) + y * W + (i & 127)];
    }
    __syncthreads();
    __hip_bfloat16* op = xp + ((size_t)b * 130 + yp) * (130 * 72);
    for (int i = tid; i < 130 * 72; i += 256) {
        int xpx = i / 72, c = i - xpx * 72;
        int xx = xpx - 1;
        float v = 0.f;
        if (interior && xx >= 0 && xx < W && c < CIN) v = xs[c * W + xx];
        op[i] = __float2bfloat16(v);
    }
}

// ===================== K0b: pack w -> [3 ky][256 oc][232] bf16 =====================
// slot s (<216): kx = s/72, ic = s%72 ; value = w[oc][ic][ky][kx] (0 if ic>=66)
// slots 216..231 zero.
__global__ __launch_bounds__(256) void k_pack_w(const float* __restrict__ w,
                                                __hip_bfloat16* __restrict__ wp)
{
    const int oc  = blockIdx.x;
    const int tid = threadIdx.x;
    for (int t = tid; t < 3 * 232; t += 256) {
        int ky = t / 232, s = t - ky * 232;
        float v = 0.f;
        if (s < 216) {
            int kx = s / 72, ic = s - kx * 72;
            if (ic < CIN) v = w[((size_t)(oc * CIN + ic) * 3 + ky) * 3 + kx];
        }
        wp[((size_t)ky * 256 + oc) * 232 + s] = __float2bfloat16(v);
    }
}

// ===================== K1: 3x3 conv via implicit-GEMM MFMA =====================
// grid (1024 = b*128+y, 2 ocg), block 256 = 4 waves (2M x 2N)
// block tile: 128 pos x 128 oc ; wave tile 64x64 ; K = 3ky x 224(=7*32)
__global__ __launch_bounds__(256, 2) void k_conv3x3_mfma(
    const __hip_bfloat16* __restrict__ xp,   // [8][130][130][72]
    const __hip_bfloat16* __restrict__ wp,   // [3][256][232]
    const float* __restrict__ bias,
    __hip_bfloat16* __restrict__ out)        // [8][256][128][128]
{
    constexpr int SB = 232;                  // B LDS row stride (bf16)
    __shared__ __hip_bfloat16 ash[9392];     // 130*72 = 9360 + 32 zero pad
    __shared__ __hip_bfloat16 bsh[128 * SB];

    const int tid = threadIdx.x;
    const int ln  = tid & 63;
    const int wv  = tid >> 6;
    const int wm  = (wv >> 1) * 64;
    const int wn  = (wv & 1) * 64;
    const int l15 = ln & 15;
    const int lhi = ln >> 4;

    const int by  = blockIdx.x;              // b*128 + y
    const int b   = by >> 7;
    const int y   = by & 127;
    const int ocb = blockIdx.y * 128;

    if (tid < 32) ash[9360 + tid] = __float2bfloat16(0.f);

    f32x4 acc[4][4] = {};

    for (int ky = 0; ky < 3; ++ky) {
        __syncthreads();
        // ---- stage A: one padded row (contiguous 18720 B) ----
        {
            const char* g = (const char*)(xp + ((size_t)b * 130 + y + ky) * 9360);
            for (int off = wv * 1024; off < 18720; off += 4096) {
                int o = off + ln * 16;
                if (o < 18720)
                    __builtin_amdgcn_global_load_lds(
                        (const __attribute__((address_space(1))) void*)(g + o),
                        (__attribute__((address_space(3))) void*)((char*)ash + off),
                        16, 0, 0);
            }
        }
        // ---- stage B: 128 oc rows of 232 (contiguous 59392 B) ----
        {
            const char* g = (const char*)(wp + ((size_t)ky * 256 + ocb) * SB);
            for (int off = wv * 1024; off < 59392; off += 4096) {
                int o = off + ln * 16;
                if (o < 59392)
                    __builtin_amdgcn_global_load_lds(
                        (const __attribute__((address_space(1))) void*)(g + o),
                        (__attribute__((address_space(3))) void*)((char*)bsh + off),
                        16, 0, 0);
            }
        }
        __syncthreads();

#pragma unroll
        for (int ks = 0; ks < 7; ++ks) {
            bf16x8 a[4], bq[4];
#pragma unroll
            for (int m = 0; m < 4; ++m) {
                int pos = wm + m * 16 + l15;
                a[m] = *(const bf16x8*)((const char*)ash + pos * 144 + ks * 64 + lhi * 16);
            }
#pragma unroll
            for (int n = 0; n < 4; ++n) {
                int oc = wn + n * 16 + l15;
                bq[n] = *(const bf16x8*)((const char*)bsh + oc * (SB * 2) + ks * 64 + lhi * 16);
            }
#pragma unroll
            for (int m = 0; m < 4; ++m)
#pragma unroll
                for (int n = 0; n < 4; ++n)
                    acc[m][n] = __builtin_amdgcn_mfma_f32_16x16x32_bf16(
                        a[m], bq[n], acc[m][n], 0, 0, 0);
        }
    }

    // ---- epilogue: bias + relu -> bf16, 4 consecutive x per lane ----
#pragma unroll
    for (int n = 0; n < 4; ++n) {
        int oc = ocb + wn + n * 16 + l15;
        float bb = bias[oc];
#pragma unroll
        for (int m = 0; m < 4; ++m) {
            int posbase = wm + m * 16 + lhi * 4;
            bh4 st;
#pragma unroll
            for (int r = 0; r < 4; ++r) {
                float v = acc[m][n][r] + bb;
                v = v > 0.f ? v : 0.f;
                st.v[r] = __float2bfloat16(v);
            }
            *(bh4*)&out[(((size_t)b * C1 + oc) * H + y) * W + posbase] = st;
        }
    }
}

// ===================== K2: 1x1 conv (256 -> 64) =====================
__global__ __launch_bounds__(256) void k_conv1x1(
    const __hip_bfloat16* __restrict__ xin, const float* __restrict__ w2,
    const float* __restrict__ b2, float* __restrict__ out)
{
    const int tid = threadIdx.x;
    const int pix = blockIdx.x * 256 + tid;
    const int b   = pix >> 14;
    const int sp  = pix & 16383;

    __shared__ float wsh[64 * 64];  // [c][o]
    float acc[64];
#pragma unroll
    for (int o = 0; o < 64; ++o) acc[o] = 0.f;

    for (int cc = 0; cc < 4; ++cc) {
        __syncthreads();
        for (int i = tid; i < 64 * 64; i += 256) {
            int c = i >> 6, o = i & 63;
            wsh[i] = w2[o * 256 + cc * 64 + c];
        }
        __syncthreads();
        const __hip_bfloat16* xp = xin + ((size_t)(b * 256 + cc * 64) * 16384) + sp;
        for (int c = 0; c < 64; ++c) {
            float xv = __bfloat162float(xp[(size_t)c * 16384]);
#pragma unroll
            for (int o = 0; o < 64; ++o) acc[o] += wsh[c * 64 + o] * xv;
        }
    }
    float* op = out + (size_t)b * 64 * 16384 + sp;
#pragma unroll
    for (int o = 0; o < 64; ++o) op[(size_t)o * 16384] = acc[o] + b2[o];
}

// ===================== K3: bilinear sample + coords -> X0 =====================
__global__ __launch_bounds__(128) void k_sample(
    const float* __restrict__ feat2, const float* __restrict__ ipoly,
    const float* __restrict__ cpoly, const int* __restrict__ ind,
    float* __restrict__ X0)
{
    const int v  = threadIdx.x;
    const int p  = blockIdx.x;
    const int cg = blockIdx.y;

    float px = ipoly[(p * V + v) * 2 + 0];
    float py = ipoly[(p * V + v) * 2 + 1];
    float ix = px - 0.5f, iy = py - 0.5f;
    float x0f = floorf(ix), y0f = floorf(iy);
    float wx = ix - x0f, wy = iy - y0f;
    int x0 = (int)x0f, y0 = (int)y0f;
    int b  = ind[p];

    int   xsv[2] = {x0, x0 + 1}, ysv[2] = {y0, y0 + 1};
    float wxs[2] = {1.f - wx, wx}, wys[2] = {1.f - wy, wy};
    float cw[4]; int cbase[4];
#pragma unroll
    for (int jy = 0; jy < 2; ++jy)
#pragma unroll
        for (int jx = 0; jx < 2; ++jx) {
            int xi = xsv[jx], yi = ysv[jy];
            bool ok = (xi >= 0) && (xi < W) && (yi >= 0) && (yi < H);
            int xc = min(max(xi, 0), W - 1);
            int yc = min(max(yi, 0), H - 1);
            cw[jy * 2 + jx]    = wys[jy] * wxs[jx] * (ok ? 1.f : 0.f);
            cbase[jy * 2 + jx] = yc * W + xc;
        }

    const float* fb = feat2 + (size_t)b * C2 * H * W + (size_t)cg * 16 * H * W;
    float* xo = X0 + ((size_t)p * FD + cg * 16) * V + v;
    for (int c = 0; c < 16; ++c) {
        const float* fc = fb + (size_t)c * H * W;
        float val = fc[cbase[0]] * cw[0] + fc[cbase[1]] * cw[1] +
                    fc[cbase[2]] * cw[2] + fc[cbase[3]] * cw[3];
        xo[(size_t)c * V] = val;
    }
    if (cg == 0) {
        X0[((size_t)p * FD + 64) * V + v] = cpoly[(p * V + v) * 2 + 0] * RO;
        X0[((size_t)p * FD + 65) * V + v] = cpoly[(p * V + v) * 2 + 1] * RO;
    }
}

// ===================== K4: circular dilated conv + relu + bn (+res) =====================
template <int DIL>
__global__ __launch_bounds__(256) void k_snake(
    const float* __restrict__ xin, int xin_pstride, int Cin,
    const float* __restrict__ w, const float* __restrict__ bias,
    const float* __restrict__ gamma, const float* __restrict__ beta,
    const float* __restrict__ resin,
    float* __restrict__ out)
{
    constexpr int W2  = V + 8 * DIL;
    constexpr int WIN = 16 + 8 * DIL;
    const int tid = threadIdx.x;
    const int ocl = tid & 31;
    const int vg  = tid >> 5;
    const int v0  = vg * 16;
    const int p   = blockIdx.x;
    const int oc  = blockIdx.y * 32 + ocl;

    __shared__ float xs[64 * W2];
    float acc[16];
#pragma unroll
    for (int i = 0; i < 16; ++i) acc[i] = 0.f;

    const float* xb = xin + (size_t)p * xin_pstride;
    for (int icc = 0; icc < Cin; icc += 64) {
        int csz = min(64, Cin - icc);
        __syncthreads();
        for (int i = tid; i < csz * W2; i += 256) {
            int ic = i / W2, j = i % W2;
            xs[i] = xb[(size_t)(icc + ic) * V + ((j + V - 4 * DIL) & (V - 1))];
        }
        __syncthreads();
        const float* wb = w + ((size_t)oc * Cin + icc) * 9;
        for (int ic = 0; ic < csz; ++ic) {
            float wk[9];
#pragma unroll
            for (int k = 0; k < 9; ++k) wk[k] = wb[ic * 9 + k];
            float xw[WIN];
#pragma unroll
            for (int t = 0; t < WIN; ++t) xw[t] = xs[ic * W2 + v0 + t];
#pragma unroll
            for (int k = 0; k < 9; ++k)
#pragma unroll
                for (int vv = 0; vv < 16; ++vv)
                    acc[vv] += wk[k] * xw[vv + k * DIL];
        }
    }

    float bb = bias[oc], gg = gamma[oc], bt = beta[oc];
    float* op = out + (size_t)p * (SCH * V) + (size_t)oc * V + v0;
    const float* rp = resin ? (resin + (size_t)p * (SCH * V) + (size_t)oc * V + v0) : nullptr;
#pragma unroll
    for (int vv = 0; vv < 16; ++vv) {
        float yv = acc[vv] + bb;
        yv = yv > 0.f ? yv : 0.f;
        yv = yv * gg + bt;
        if (rp) yv += rp[vv];
        op[vv] = yv;
    }
}

// ===================== K5: generic per-vertex 1x1 conv =====================
__global__ __launch_bounds__(256) void k_vconv(
    const float* __restrict__ xin, int pstride, int C,
    const float* __restrict__ w, int wstride,
    const float* __restrict__ bias,
    const float* __restrict__ pbias,
    int O, int relu,
    float* __restrict__ out)
{
    const int tid = threadIdx.x;
    const int ot  = tid >> 5;
    const int vt  = tid & 31;
    const int v4  = vt * 4;
    const int p   = blockIdx.x;
    const int ob  = blockIdx.y * 64;

    __shared__ __align__(16) float xsh[64 * V];
    __shared__ float wsh[64 * 64];   // [c][o]
    float acc[8][4];
#pragma unroll
    for (int o = 0; o < 8; ++o)
#pragma unroll
        for (int j = 0; j < 4; ++j) acc[o][j] = 0.f;

    const float* xb = xin + (size_t)p * pstride;
    for (int cc = 0; cc < C; cc += 64) {
        __syncthreads();
        for (int i = tid; i < 64 * V; i += 256) xsh[i] = xb[(size_t)cc * V + i];
        for (int i = tid; i < 64 * 64; i += 256) {
            int c = i >> 6, o = i & 63;
            wsh[i] = w[(size_t)(ob + o) * wstride + cc + c];
        }
        __syncthreads();
        for (int c = 0; c < 64; ++c) {
            float4 xv = *(const float4*)&xsh[c * V + v4];
#pragma unroll
            for (int o = 0; o < 8; ++o) {
                float wv = wsh[c * 64 + ot * 8 + o];
                acc[o][0] += wv * xv.x;
                acc[o][1] += wv * xv.y;
                acc[o][2] += wv * xv.z;
                acc[o][3] += wv * xv.w;
            }
        }
    }
#pragma unroll
    for (int o = 0; o < 8; ++o) {
        int og = ob + ot * 8 + o;
        float bb = (bias ? bias[og] : 0.f) + (pbias ? pbias[(size_t)p * O + og] : 0.f);
        float4 r;
        r.x = acc[o][0] + bb; r.y = acc[o][1] + bb;
        r.z = acc[o][2] + bb; r.w = acc[o][3] + bb;
        if (relu) {
            r.x = r.x > 0.f ? r.x : 0.f; r.y = r.y > 0.f ? r.y : 0.f;
            r.z = r.z > 0.f ? r.z : 0.f; r.w = r.w > 0.f ? r.w : 0.f;
        }
        *(float4*)&out[(size_t)p * O * V + (size_t)og * V + v4] = r;
    }
}

// ===================== K6: max over vertices =====================
__global__ __launch_bounds__(256) void k_gmax(const float* __restrict__ fused,
                                              float* __restrict__ g)
{
    int p = blockIdx.x, o = threadIdx.x;
    const float4* fp = (const float4*)(fused + ((size_t)p * 256 + o) * V);
    float m = -3.4e38f;
    for (int i = 0; i < V / 4; ++i) {
        float4 t = fp[i];
        m = fmaxf(m, fmaxf(fmaxf(t.x, t.y), fmaxf(t.z, t.w)));
    }
    g[(size_t)p * 256 + o] = m;
}

// ===================== K7: gc[p][o] = pb1[o] + pw1[o,0:256] . g[p] =====================
__global__ __launch_bounds__(256) void k_gc(const float* __restrict__ g,
                                            const float* __restrict__ pw1,
                                            const float* __restrict__ pb1,
                                            float* __restrict__ gc)
{
    int p = blockIdx.x, o = threadIdx.x;
    __shared__ float gl[256];
    gl[o] = g[(size_t)p * 256 + o];
    __syncthreads();
    float a = pb1[o];
    const float* wr = pw1 + (size_t)o * 1280;
    for (int c = 0; c < 256; ++c) a += wr[c] * gl[c];
    gc[(size_t)p * 256 + o] = a;
}

// ===================== K8: final pw3 + compose output =====================
__global__ __launch_bounds__(128) void k_final(const float* __restrict__ h2,
                                               const float* __restrict__ pw3,
                                               const float* __restrict__ pb3,
                                               const float* __restrict__ ipoly,
                                               float* __restrict__ outp)
{
    int p = blockIdx.x, v = threadIdx.x;
    __shared__ float w3[128];
    w3[v] = pw3[v];
    __syncthreads();
    float a0 = pb3[0], a1 = pb3[1];
    const float* hp = h2 + (size_t)p * 64 * V + v;
    for (int c = 0; c < 64; ++c) {
        float hv = hp[(size_t)c * V];
        a0 += w3[c] * hv;
        a1 += w3[64 + c] * hv;
    }
    int idx = (p * V + v) * 2;
    outp[idx]     = ipoly[idx] * RO + a0;
    outp[idx + 1] = ipoly[idx + 1] * RO + a1;
}

// ===================== host =====================
extern "C" void kernel_launch(void* const* d_in, const int* in_sizes, int n_in,
                              void* d_out, int out_size, void* d_ws, size_t ws_size,
                              hipStream_t stream)
{
    const float* cnn   = (const float*)d_in[0];
    const float* ipoly = (const float*)d_in[1];
    const float* cpoly = (const float*)d_in[2];
    const int*   ind   = (const int*)d_in[3];
    const float* pw1c  = (const float*)d_in[4];
    const float* pb1c  = (const float*)d_in[5];
    const float* pw2c  = (const float*)d_in[6];
    const float* pb2c  = (const float*)d_in[7];
    const float* hw    = (const float*)d_in[8];
    const float* hb    = (const float*)d_in[9];
    const float* hg    = (const float*)d_in[10];
    const float* hbt   = (const float*)d_in[11];
    const float* rw    = (const float*)d_in[12];
    const float* rb    = (const float*)d_in[13];
    const float* rg    = (const float*)d_in[14];
    const float* rbt   = (const float*)d_in[15];
    const float* fw    = (const float*)d_in[16];
    const float* fb    = (const float*)d_in[17];
    const float* ppw1  = (const float*)d_in[18];
    const float* ppb1  = (const float*)d_in[19];
    const float* ppw2  = (const float*)d_in[20];
    const float* ppb2  = (const float*)d_in[21];
    const float* ppw3  = (const float*)d_in[22];
    const float* ppb3  = (const float*)d_in[23];
    float* outp = (float*)d_out;

    char* ws = (char*)d_ws;
    // layout (bytes):
    //   [0, 67108864)         feat1 (bf16) / later states (f32)   -- time-aliased
    //   [67108864, ...)       xp (19.5MB) + wp (0.35MB)  -- dead after conv3x3
    //                         then feat2 / fused / g / gc / h2 overlay same region
    //   [100663296, ...)      X0
    __hip_bfloat16* feat1 = (__hip_bfloat16*)(ws);
    float* states = (float*)(ws);
    __hip_bfloat16* xp  = (__hip_bfloat16*)(ws + 67108864);
    __hip_bfloat16* wpk = (__hip_bfloat16*)(ws + 86577664);   // 67108864+19468800
    float* feat2  = (float*)(ws + 67108864);
    float* fused  = (float*)(ws + 67108864);
    float* h1     = fused;
    float* gbuf   = (float*)(ws + 67108864 + 16777216);
    float* gcbuf  = (float*)(ws + 67108864 + 16777216 + 131072);
    float* h2     = (float*)(ws + 67108864 + 16777216 + 262144);
    float* X0     = (float*)(ws + 100663296);

    // 0) pack x and w for MFMA conv
    k_pack_x<<<dim3(8 * 130), 256, 0, stream>>>(cnn, xp);
    k_pack_w<<<dim3(256), 256, 0, stream>>>(pw1c, wpk);
    // 1) 3x3 conv + relu -> feat1 (bf16), implicit GEMM MFMA
    k_conv3x3_mfma<<<dim3(1024, 2), 256, 0, stream>>>(xp, wpk, pb1c, feat1);
    // 2) 1x1 conv -> feat2
    k_conv1x1<<<dim3(512), 256, 0, stream>>>(feat1, pw2c, pb2c, feat2);
    // 3) bilinear sample + coords -> X0
    k_sample<<<dim3(NP, 4), 128, 0, stream>>>(feat2, ipoly, cpoly, ind, X0);
    // 4) head conv (d=1, Cin=66) -> states block 0
    k_snake<1><<<dim3(NP, 4), 256, 0, stream>>>(X0, FD * V, FD, hw, hb, hg, hbt,
                                                nullptr, states);
    // 5..11) residual dilated convs
    const int dil[NRES] = {1, 1, 1, 2, 2, 4, 4};
    for (int i = 0; i < NRES; ++i) {
        const float* xin = states + (size_t)i * SD * V;
        float* yout      = states + (size_t)(i + 1) * SD * V;
        const float* wi  = rw + (size_t)i * SD * SD * 9;
        if (dil[i] == 1)
            k_snake<1><<<dim3(NP, 4), 256, 0, stream>>>(xin, SCH * V, SD, wi,
                rb + i * SD, rg + i * SD, rbt + i * SD, xin, yout);
        else if (dil[i] == 2)
            k_snake<2><<<dim3(NP, 4), 256, 0, stream>>>(xin, SCH * V, SD, wi,
                rb + i * SD, rg + i * SD, rbt + i * SD, xin, yout);
        else
            k_snake<4><<<dim3(NP, 4), 256, 0, stream>>>(xin, SCH * V, SD, wi,
                rb + i * SD, rg + i * SD, rbt + i * SD, xin, yout);
    }
    // 12) fused 1x1 over state -> fused (p,256,V)
    k_vconv<<<dim3(NP, 4), 256, 0, stream>>>(states, SCH * V, SCH, fw, SCH,
                                             fb, nullptr, 256, 0, fused);
    // 13) g = max over vertices
    k_gmax<<<dim3(NP), 256, 0, stream>>>(fused, gbuf);
    // 14) gc = pb1 + pw1[:, :256] @ g
    k_gc<<<dim3(NP), 256, 0, stream>>>(gbuf, ppw1, ppb1, gcbuf);
    // 15) h1 = relu(pw1[:, 256:] @ state + gc)
    k_vconv<<<dim3(NP, 4), 256, 0, stream>>>(states, SCH * V, SCH, ppw1 + 256, 1280,
                                             nullptr, gcbuf, 256, 1, h1);
    // 16) h2 = relu(pw2 @ h1 + pb2)
    k_vconv<<<dim3(NP, 1), 256, 0, stream>>>(h1, 256 * V, 256, ppw2, 256,
                                             ppb2, nullptr, 64, 1, h2);
    // 17) final: out = ipoly*RO + pw3 @ h2 + pb3
    k_final<<<dim3(NP), 128, 0, stream>>>(h2, ppw3, ppb3, ipoly, outp);
}

// Round 3
// 590.438 us; speedup vs baseline: 4.3544x; 2.6552x over previous
//
#include <hip/hip_runtime.h>
#include <hip/hip_bf16.h>

// ---- problem constants ----
constexpr int B   = 8;
constexpr int CIN = 66;
constexpr int H   = 128, W = 128;
constexpr int C1  = 256;
constexpr int NP  = 128;
constexpr int V   = 128;
constexpr int SD  = 128;
constexpr int NRES = 7;
constexpr float RO = 4.0f;

typedef __bf16 bf16x8 __attribute__((ext_vector_type(8)));
typedef float  f32x4  __attribute__((ext_vector_type(4)));
typedef unsigned short u16x8 __attribute__((ext_vector_type(8)));

__device__ inline float bfu2f(unsigned short u) {
    union { unsigned int i; float f; } c; c.i = ((unsigned)u) << 16; return c.f;
}

// ===================== K0a: pack x -> channel-last bf16 with borders =====================
__global__ __launch_bounds__(256) void k_pack_x(const float* __restrict__ x,
                                                __hip_bfloat16* __restrict__ xp)
{
    const int bi  = blockIdx.x;          // 8*130
    const int b   = bi / 130;
    const int yp  = bi % 130;
    const int tid = threadIdx.x;
    const int y   = yp - 1;
    const bool interior = (y >= 0 && y < H);

    __shared__ float xs[CIN * W];
    if (interior) {
        for (int i = tid; i < CIN * W; i += 256)
            xs[i] = x[((size_t)b * CIN + (i >> 7)) * (H * W) + y * W + (i & 127)];
    }
    __syncthreads();
    __hip_bfloat16* op = xp + ((size_t)b * 130 + yp) * (130 * 72);
    for (int i = tid; i < 130 * 72; i += 256) {
        int xpx = i / 72, c = i - xpx * 72;
        int xx = xpx - 1;
        float v = 0.f;
        if (interior && xx >= 0 && xx < W && c < CIN) v = xs[c * W + xx];
        op[i] = __float2bfloat16(v);
    }
}

// ===================== K0b: pack w -> [3 ky][256 oc][232] bf16 =====================
__global__ __launch_bounds__(256) void k_pack_w(const float* __restrict__ w,
                                                __hip_bfloat16* __restrict__ wp)
{
    const int oc  = blockIdx.x;
    const int tid = threadIdx.x;
    for (int t = tid; t < 3 * 232; t += 256) {
        int ky = t / 232, s = t - ky * 232;
        float v = 0.f;
        if (s < 216) {
            int kx = s / 72, ic = s - kx * 72;
            if (ic < CIN) v = w[((size_t)(oc * CIN + ic) * 3 + ky) * 3 + kx];
        }
        wp[((size_t)ky * 256 + oc) * 232 + s] = __float2bfloat16(v);
    }
}

// ===================== K0c: pack snake weights -> [8][9][128 oc][128 ic] bf16 =====================
__global__ __launch_bounds__(256) void k_pack_snake_w(const float* __restrict__ hw,
                                                      const float* __restrict__ rw,
                                                      __hip_bfloat16* __restrict__ wpk2)
{
    const int l  = blockIdx.x >> 7;
    const int oc = blockIdx.x & 127;
    const int tid = threadIdx.x;
    for (int t = tid; t < 9 * 128; t += 256) {
        int k = t >> 7, ic = t & 127;
        float v = 0.f;
        if (l == 0) {
            if (ic < 66) v = hw[((size_t)oc * 66 + ic) * 9 + k];
        } else {
            v = rw[((((size_t)(l - 1) * 128 + oc) * 128) + ic) * 9 + k];
        }
        wpk2[(((size_t)l * 9 + k) * 128 + oc) * 128 + ic] = __float2bfloat16(v);
    }
}

// ===================== K0d: generic f32 matrix -> bf16 pack =====================
__global__ __launch_bounds__(256) void k_pack_mat(const float* __restrict__ src,
                                                  __hip_bfloat16* __restrict__ dst,
                                                  int rows, int cols, int rstride, int coff)
{
    int n = rows * cols;
    for (int i = blockIdx.x * 256 + threadIdx.x; i < n; i += gridDim.x * 256) {
        int r = i / cols, c = i - r * cols;
        dst[i] = __float2bfloat16(src[(size_t)r * rstride + coff + c]);
    }
}

// ===================== K1: 3x3 conv via implicit-GEMM MFMA =====================
// out: channel-last feat1 [8][128 y][128 x][256 oc] bf16
__global__ __launch_bounds__(256, 2) void k_conv3x3_mfma(
    const __hip_bfloat16* __restrict__ xp,   // [8][130][130][72]
    const __hip_bfloat16* __restrict__ wp,   // [3][256][232]
    const float* __restrict__ bias,
    __hip_bfloat16* __restrict__ out)
{
    constexpr int SB = 232;
    __shared__ __hip_bfloat16 ash[9392];
    __shared__ __hip_bfloat16 bsh[128 * SB];

    const int tid = threadIdx.x;
    const int ln  = tid & 63;
    const int wv  = tid >> 6;
    const int wm  = (wv >> 1) * 64;
    const int wn  = (wv & 1) * 64;
    const int l15 = ln & 15;
    const int lhi = ln >> 4;

    const int by  = blockIdx.x;
    const int b   = by >> 7;
    const int y   = by & 127;
    const int ocb = blockIdx.y * 128;

    if (tid < 32) ash[9360 + tid] = __float2bfloat16(0.f);

    f32x4 acc[4][4] = {};

    for (int ky = 0; ky < 3; ++ky) {
        __syncthreads();
        {
            const char* g = (const char*)(xp + ((size_t)b * 130 + y + ky) * 9360);
            for (int off = wv * 1024; off < 18720; off += 4096) {
                int o = off + ln * 16;
                if (o < 18720)
                    __builtin_amdgcn_global_load_lds(
                        (const __attribute__((address_space(1))) void*)(g + o),
                        (__attribute__((address_space(3))) void*)((char*)ash + off),
                        16, 0, 0);
            }
        }
        {
            const char* g = (const char*)(wp + ((size_t)ky * 256 + ocb) * SB);
            for (int off = wv * 1024; off < 59392; off += 4096) {
                int o = off + ln * 16;
                if (o < 59392)
                    __builtin_amdgcn_global_load_lds(
                        (const __attribute__((address_space(1))) void*)(g + o),
                        (__attribute__((address_space(3))) void*)((char*)bsh + off),
                        16, 0, 0);
            }
        }
        __syncthreads();

#pragma unroll
        for (int ks = 0; ks < 7; ++ks) {
            bf16x8 a[4], bq[4];
#pragma unroll
            for (int m = 0; m < 4; ++m) {
                int pos = wm + m * 16 + l15;
                a[m] = *(const bf16x8*)((const char*)ash + pos * 144 + ks * 64 + lhi * 16);
            }
#pragma unroll
            for (int n = 0; n < 4; ++n) {
                int oc = wn + n * 16 + l15;
                bq[n] = *(const bf16x8*)((const char*)bsh + oc * (SB * 2) + ks * 64 + lhi * 16);
            }
#pragma unroll
            for (int m = 0; m < 4; ++m)
#pragma unroll
                for (int n = 0; n < 4; ++n)
                    acc[m][n] = __builtin_amdgcn_mfma_f32_16x16x32_bf16(
                        a[m], bq[n], acc[m][n], 0, 0, 0);
        }
    }

    // epilogue: bias + relu -> channel-last bf16
#pragma unroll
    for (int n = 0; n < 4; ++n) {
        int oc = ocb + wn + n * 16 + l15;
        float bb = bias[oc];
#pragma unroll
        for (int m = 0; m < 4; ++m) {
#pragma unroll
            for (int r = 0; r < 4; ++r) {
                int pos = wm + m * 16 + lhi * 4 + r;
                float v = acc[m][n][r] + bb;
                v = v > 0.f ? v : 0.f;
                out[(((size_t)b * 128 + y) * 128 + pos) * 256 + oc] = __float2bfloat16(v);
            }
        }
    }
}

// ===================== K2: 1x1 conv (256 -> 64) MFMA =====================
// grid 512, 256 thr = 4 waves, each wave 64 pos x 64 oc; A direct-global, B in LDS
__global__ __launch_bounds__(256) void k_conv1x1_mfma(
    const __hip_bfloat16* __restrict__ feat1,   // [131072 pos][256]
    const __hip_bfloat16* __restrict__ w2b,     // [64][256]
    const float* __restrict__ b2,
    __hip_bfloat16* __restrict__ feat2)         // [131072 pos][64]
{
    const int tid = threadIdx.x;
    const int ln  = tid & 63;
    const int wv  = tid >> 6;
    const int wm  = wv * 64;
    const int l15 = ln & 15;
    const int lhi = ln >> 4;
    const int pos0 = blockIdx.x * 256;

    __shared__ __hip_bfloat16 wsh[64 * 136];
    for (int i = tid; i < 1024; i += 256) {
        int row = i >> 4, slot = i & 15;
        *(bf16x8*)&wsh[row * 136 + slot * 8] = *(const bf16x8*)(w2b + row * 256 + slot * 8);
    }
    __syncthreads();

    f32x4 acc[4][4] = {};
#pragma unroll
    for (int kk = 0; kk < 8; ++kk) {
        bf16x8 a[4], bq[4];
#pragma unroll
        for (int m = 0; m < 4; ++m)
            a[m] = *(const bf16x8*)(feat1 + (size_t)(pos0 + wm + m * 16 + l15) * 256 + kk * 32 + lhi * 8);
#pragma unroll
        for (int n = 0; n < 4; ++n)
            bq[n] = *(const bf16x8*)&wsh[(n * 16 + l15) * 136 + kk * 32 + lhi * 8];
#pragma unroll
        for (int m = 0; m < 4; ++m)
#pragma unroll
            for (int n = 0; n < 4; ++n)
                acc[m][n] = __builtin_amdgcn_mfma_f32_16x16x32_bf16(a[m], bq[n], acc[m][n], 0, 0, 0);
    }
#pragma unroll
    for (int n = 0; n < 4; ++n) {
        int og = n * 16 + l15;
        float bb = b2[og];
#pragma unroll
        for (int m = 0; m < 4; ++m)
#pragma unroll
            for (int r = 0; r < 4; ++r) {
                int pos = pos0 + wm + m * 16 + lhi * 4 + r;
                feat2[(size_t)pos * 64 + og] = __float2bfloat16(acc[m][n][r] + bb);
            }
    }
}

// ===================== K3: bilinear sample + coords -> X0 [p][v][128] bf16 =====================
__global__ __launch_bounds__(128) void k_sample(
    const __hip_bfloat16* __restrict__ feat2, const float* __restrict__ ipoly,
    const float* __restrict__ cpoly, const int* __restrict__ ind,
    __hip_bfloat16* __restrict__ X0)
{
    const int p = blockIdx.x;
    const int v = threadIdx.x;

    float px = ipoly[(p * V + v) * 2 + 0];
    float py = ipoly[(p * V + v) * 2 + 1];
    float ix = px - 0.5f, iy = py - 0.5f;
    float x0f = floorf(ix), y0f = floorf(iy);
    float wx = ix - x0f, wy = iy - y0f;
    int x0 = (int)x0f, y0 = (int)y0f;

    int   xsv[2] = {x0, x0 + 1}, ysv[2] = {y0, y0 + 1};
    float wxs[2] = {1.f - wx, wx}, wys[2] = {1.f - wy, wy};
    float cw[4]; int cbase[4];
#pragma unroll
    for (int jy = 0; jy < 2; ++jy)
#pragma unroll
        for (int jx = 0; jx < 2; ++jx) {
            int xi = xsv[jx], yi = ysv[jy];
            bool ok = (xi >= 0) && (xi < W) && (yi >= 0) && (yi < H);
            int xc = min(max(xi, 0), W - 1);
            int yc = min(max(yi, 0), H - 1);
            cw[jy * 2 + jx]    = wys[jy] * wxs[jx] * (ok ? 1.f : 0.f);
            cbase[jy * 2 + jx] = yc * W + xc;
        }

    const __hip_bfloat16* fb = feat2 + (size_t)ind[p] * (16384 * 64);
    __hip_bfloat16* xr = X0 + ((size_t)p * V + v) * 128;
#pragma unroll
    for (int ch = 0; ch < 8; ++ch) {
        float s[8];
#pragma unroll
        for (int e = 0; e < 8; ++e) s[e] = 0.f;
#pragma unroll
        for (int j = 0; j < 4; ++j) {
            u16x8 t = *(const u16x8*)(fb + (size_t)cbase[j] * 64 + ch * 8);
#pragma unroll
            for (int e = 0; e < 8; ++e) s[e] += cw[j] * bfu2f(t[e]);
        }
#pragma unroll
        for (int e = 0; e < 8; ++e) xr[ch * 8 + e] = __float2bfloat16(s[e]);
    }
    xr[64] = __float2bfloat16(cpoly[(p * V + v) * 2 + 0] * RO);
    xr[65] = __float2bfloat16(cpoly[(p * V + v) * 2 + 1] * RO);
    for (int c = 66; c < 128; ++c) xr[c] = __float2bfloat16(0.f);
}

// ===================== K4: snake circular conv layer (MFMA) =====================
// grid 128 (p), 256 thr = 4 waves 2x2, wave 64 pos x 64 oc.
// x staged once in LDS [128 v][136]; weights direct from global (L2-hot).
__global__ __launch_bounds__(256) void k_snake_mfma(
    const __hip_bfloat16* __restrict__ xin,   // [NP][V][128]
    const __hip_bfloat16* __restrict__ wl,    // [9][128 oc][128 ic]
    const float* __restrict__ bias, const float* __restrict__ gamma,
    const float* __restrict__ beta,
    const __hip_bfloat16* __restrict__ resin, // nullable, [NP][V][128]
    __hip_bfloat16* __restrict__ out,         // [NP][V][128]
    int dil)
{
    const int tid = threadIdx.x;
    const int ln  = tid & 63;
    const int wv  = tid >> 6;
    const int wm  = (wv >> 1) * 64;
    const int wn  = (wv & 1) * 64;
    const int l15 = ln & 15;
    const int lhi = ln >> 4;
    const int p   = blockIdx.x;

    __shared__ __hip_bfloat16 xs[128 * 136];
    const __hip_bfloat16* xb = xin + (size_t)p * (V * 128);
    for (int i = tid; i < 2048; i += 256) {
        int v = i >> 4, slot = i & 15;
        *(bf16x8*)&xs[v * 136 + slot * 8] = *(const bf16x8*)(xb + v * 128 + slot * 8);
    }
    __syncthreads();

    f32x4 acc[4][4] = {};
#pragma unroll
    for (int k = 0; k < 9; ++k) {
        const int shift = (k - 4) * dil + 256;  // keep positive before &127
        const __hip_bfloat16* wk = wl + (size_t)k * (128 * 128);
#pragma unroll
        for (int kc = 0; kc < 4; ++kc) {
            bf16x8 a[4], bq[4];
#pragma unroll
            for (int m = 0; m < 4; ++m) {
                int row = (wm + m * 16 + l15 + shift) & 127;
                a[m] = *(const bf16x8*)&xs[row * 136 + kc * 32 + lhi * 8];
            }
#pragma unroll
            for (int n = 0; n < 4; ++n)
                bq[n] = *(const bf16x8*)(wk + (size_t)(wn + n * 16 + l15) * 128 + kc * 32 + lhi * 8);
#pragma unroll
            for (int m = 0; m < 4; ++m)
#pragma unroll
                for (int n = 0; n < 4; ++n)
                    acc[m][n] = __builtin_amdgcn_mfma_f32_16x16x32_bf16(a[m], bq[n], acc[m][n], 0, 0, 0);
        }
    }

#pragma unroll
    for (int n = 0; n < 4; ++n) {
        int oc = wn + n * 16 + l15;
        float bb = bias[oc], gg = gamma[oc], bt = beta[oc];
#pragma unroll
        for (int m = 0; m < 4; ++m)
#pragma unroll
            for (int r = 0; r < 4; ++r) {
                int pos = wm + m * 16 + lhi * 4 + r;
                size_t idx = ((size_t)p * V + pos) * 128 + oc;
                float v = acc[m][n][r] + bb;
                v = v > 0.f ? v : 0.f;
                v = v * gg + bt;
                if (resin) v += __bfloat162float(resin[idx]);
                out[idx] = __float2bfloat16(v);
            }
    }
}

// ===================== K5: vconv over concat states (K=1024, O=256) =====================
// grid (NP, 2), 256 thr = 4 waves 2x2, wave 64 pos x 64 oc. All operands global.
__global__ __launch_bounds__(256) void k_vconv1024(
    const __hip_bfloat16* __restrict__ xin,   // states [8][NP][V][128]
    const __hip_bfloat16* __restrict__ wb,    // [256][1024]
    const float* __restrict__ fbias,          // nullable [256]
    const float* __restrict__ pbias,          // nullable [NP][256]
    int relu,
    __hip_bfloat16* __restrict__ out)         // [NP][V][256]
{
    const int tid = threadIdx.x;
    const int ln  = tid & 63;
    const int wv  = tid >> 6;
    const int wm  = (wv >> 1) * 64;
    const int wn  = (wv & 1) * 64;
    const int l15 = ln & 15;
    const int lhi = ln >> 4;
    const int p   = blockIdx.x;
    const int ocb = blockIdx.y * 128;

    f32x4 acc[4][4] = {};
    for (int s = 0; s < 8; ++s) {
        const __hip_bfloat16* xa = xin + ((size_t)s * NP + p) * (V * 128);
#pragma unroll
        for (int kc = 0; kc < 4; ++kc) {
            bf16x8 a[4], bq[4];
#pragma unroll
            for (int m = 0; m < 4; ++m)
                a[m] = *(const bf16x8*)(xa + (size_t)(wm + m * 16 + l15) * 128 + kc * 32 + lhi * 8);
#pragma unroll
            for (int n = 0; n < 4; ++n)
                bq[n] = *(const bf16x8*)(wb + (size_t)(ocb + wn + n * 16 + l15) * 1024 + s * 128 + kc * 32 + lhi * 8);
#pragma unroll
            for (int m = 0; m < 4; ++m)
#pragma unroll
                for (int n = 0; n < 4; ++n)
                    acc[m][n] = __builtin_amdgcn_mfma_f32_16x16x32_bf16(a[m], bq[n], acc[m][n], 0, 0, 0);
        }
    }
#pragma unroll
    for (int n = 0; n < 4; ++n) {
        int og = ocb + wn + n * 16 + l15;
        float bb = (fbias ? fbias[og] : 0.f) + (pbias ? pbias[(size_t)p * 256 + og] : 0.f);
#pragma unroll
        for (int m = 0; m < 4; ++m)
#pragma unroll
            for (int r = 0; r < 4; ++r) {
                int pos = wm + m * 16 + lhi * 4 + r;
                float v = acc[m][n][r] + bb;
                if (relu) v = v > 0.f ? v : 0.f;
                out[((size_t)p * V + pos) * 256 + og] = __float2bfloat16(v);
            }
    }
}

// ===================== K6: h2 = relu(pw2 @ h1 + pb2)  (K=256, O=64) =====================
// grid NP, 128 thr = 2 waves, wave 64 pos x 64 oc
__global__ __launch_bounds__(128) void k_h2(
    const __hip_bfloat16* __restrict__ h1,    // [NP][V][256]
    const __hip_bfloat16* __restrict__ w2b,   // [64][256]
    const float* __restrict__ pb2,
    __hip_bfloat16* __restrict__ h2)          // [NP][V][64]
{
    const int tid = threadIdx.x;
    const int ln  = tid & 63;
    const int wv  = tid >> 6;
    const int wm  = wv * 64;
    const int l15 = ln & 15;
    const int lhi = ln >> 4;
    const int p   = blockIdx.x;

    f32x4 acc[4][4] = {};
#pragma unroll
    for (int kk = 0; kk < 8; ++kk) {
        bf16x8 a[4], bq[4];
#pragma unroll
        for (int m = 0; m < 4; ++m)
            a[m] = *(const bf16x8*)(h1 + ((size_t)p * V + wm + m * 16 + l15) * 256 + kk * 32 + lhi * 8);
#pragma unroll
        for (int n = 0; n < 4; ++n)
            bq[n] = *(const bf16x8*)(w2b + (size_t)(n * 16 + l15) * 256 + kk * 32 + lhi * 8);
#pragma unroll
        for (int m = 0; m < 4; ++m)
#pragma unroll
            for (int n = 0; n < 4; ++n)
                acc[m][n] = __builtin_amdgcn_mfma_f32_16x16x32_bf16(a[m], bq[n], acc[m][n], 0, 0, 0);
    }
#pragma unroll
    for (int n = 0; n < 4; ++n) {
        int og = n * 16 + l15;
        float bb = pb2[og];
#pragma unroll
        for (int m = 0; m < 4; ++m)
#pragma unroll
            for (int r = 0; r < 4; ++r) {
                int pos = wm + m * 16 + lhi * 4 + r;
                float v = acc[m][n][r] + bb;
                v = v > 0.f ? v : 0.f;
                h2[((size_t)p * V + pos) * 64 + og] = __float2bfloat16(v);
            }
    }
}

// ===================== K7: max over vertices (fused [p][v][256] bf16) =====================
__global__ __launch_bounds__(256) void k_gmax(const __hip_bfloat16* __restrict__ fused,
                                              float* __restrict__ g)
{
    int p = blockIdx.x, o = threadIdx.x;
    float m = -3.4e38f;
    for (int v = 0; v < V; ++v)
        m = fmaxf(m, __bfloat162float(fused[((size_t)p * V + v) * 256 + o]));
    g[(size_t)p * 256 + o] = m;
}

// ===================== K8: gc[p][o] = pb1[o] + pw1[o,0:256] . g[p] =====================
__global__ __launch_bounds__(256) void k_gc(const float* __restrict__ g,
                                            const float* __restrict__ pw1,
                                            const float* __restrict__ pb1,
                                            float* __restrict__ gc)
{
    int p = blockIdx.x, o = threadIdx.x;
    __shared__ float gl[256];
    gl[o] = g[(size_t)p * 256 + o];
    __syncthreads();
    float a = pb1[o];
    const float* wr = pw1 + (size_t)o * 1280;
    for (int c = 0; c < 256; ++c) a += wr[c] * gl[c];
    gc[(size_t)p * 256 + o] = a;
}

// ===================== K9: final pw3 + compose output =====================
__global__ __launch_bounds__(128) void k_final(const __hip_bfloat16* __restrict__ h2,
                                               const float* __restrict__ pw3,
                                               const float* __restrict__ pb3,
                                               const float* __restrict__ ipoly,
                                               float* __restrict__ outp)
{
    int p = blockIdx.x, v = threadIdx.x;
    __shared__ float w3[128];
    w3[v] = pw3[v];
    __syncthreads();
    float a0 = pb3[0], a1 = pb3[1];
    const u16x8* hp = (const u16x8*)(h2 + ((size_t)p * V + v) * 64);
#pragma unroll
    for (int ch = 0; ch < 8; ++ch) {
        u16x8 t = hp[ch];
#pragma unroll
        for (int e = 0; e < 8; ++e) {
            int c = ch * 8 + e;
            float hv = bfu2f(t[e]);
            a0 += w3[c] * hv;
            a1 += w3[64 + c] * hv;
        }
    }
    int idx = (p * V + v) * 2;
    outp[idx]     = ipoly[idx] * RO + a0;
    outp[idx + 1] = ipoly[idx + 1] * RO + a1;
}

// ===================== host =====================
extern "C" void kernel_launch(void* const* d_in, const int* in_sizes, int n_in,
                              void* d_out, int out_size, void* d_ws, size_t ws_size,
                              hipStream_t stream)
{
    const float* cnn   = (const float*)d_in[0];
    const float* ipoly = (const float*)d_in[1];
    const float* cpoly = (const float*)d_in[2];
    const int*   ind   = (const int*)d_in[3];
    const float* pw1c  = (const float*)d_in[4];
    const float* pb1c  = (const float*)d_in[5];
    const float* pw2c  = (const float*)d_in[6];
    const float* pb2c  = (const float*)d_in[7];
    const float* hw    = (const float*)d_in[8];
    const float* hb    = (const float*)d_in[9];
    const float* hg    = (const float*)d_in[10];
    const float* hbt   = (const float*)d_in[11];
    const float* rw    = (const float*)d_in[12];
    const float* rb    = (const float*)d_in[13];
    const float* rg    = (const float*)d_in[14];
    const float* rbt   = (const float*)d_in[15];
    const float* fw    = (const float*)d_in[16];
    const float* fb    = (const float*)d_in[17];
    const float* ppw1  = (const float*)d_in[18];
    const float* ppb1  = (const float*)d_in[19];
    const float* ppw2  = (const float*)d_in[20];
    const float* ppb2  = (const float*)d_in[21];
    const float* ppw3  = (const float*)d_in[22];
    const float* ppb3  = (const float*)d_in[23];
    float* outp = (float*)d_out;

    char* ws = (char*)d_ws;
    // byte layout (time-aliased):
    //   [0, 64M): feat1 [131072][256] bf16  -> later:
    //       states 8x[128][128][128] bf16 = [0, 33554432)
    //       fused  = [33554432, 41943040)
    //       h1     = [41943040, 50331648)
    //       h2     = [50331648, 52428800)
    //       g      = [52428800, 52559872)
    //       gc     = [52559872, 52690944)
    //   [67108864, 86577664): xp  -> later feat2 [131072][64] bf16 (16MB)
    //   [86577664, ...): wpk, wpk2, fwb, pw1hb, pw2b, X0
    __hip_bfloat16* feat1  = (__hip_bfloat16*)(ws);
    __hip_bfloat16* states = (__hip_bfloat16*)(ws);
    __hip_bfloat16* fused  = (__hip_bfloat16*)(ws + 33554432);
    __hip_bfloat16* h1     = (__hip_bfloat16*)(ws + 41943040);
    __hip_bfloat16* h2     = (__hip_bfloat16*)(ws + 50331648);
    float*          gbuf   = (float*)(ws + 52428800);
    float*          gcbuf  = (float*)(ws + 52559872);
    __hip_bfloat16* xp     = (__hip_bfloat16*)(ws + 67108864);
    __hip_bfloat16* feat2  = (__hip_bfloat16*)(ws + 67108864);
    __hip_bfloat16* wpk    = (__hip_bfloat16*)(ws + 86577664);
    __hip_bfloat16* wpk2   = (__hip_bfloat16*)(ws + 87023104);
    __hip_bfloat16* fwb    = (__hip_bfloat16*)(ws + 89382400);
    __hip_bfloat16* pw1hb  = (__hip_bfloat16*)(ws + 89906688);
    __hip_bfloat16* pw2b   = (__hip_bfloat16*)(ws + 90430976);
    __hip_bfloat16* X0     = (__hip_bfloat16*)(ws + 90472448);

    // 0) packs
    k_pack_x<<<dim3(8 * 130), 256, 0, stream>>>(cnn, xp);
    k_pack_w<<<dim3(256), 256, 0, stream>>>(pw1c, wpk);
    k_pack_snake_w<<<dim3(8 * 128), 256, 0, stream>>>(hw, rw, wpk2);
    k_pack_mat<<<dim3(256), 256, 0, stream>>>(fw, fwb, 256, 1024, 1024, 0);
    k_pack_mat<<<dim3(256), 256, 0, stream>>>(ppw1, pw1hb, 256, 1024, 1280, 256);
    k_pack_mat<<<dim3(64), 256, 0, stream>>>(ppw2, pw2b, 64, 256, 256, 0);

    // 1) 3x3 conv + relu -> feat1 (channel-last bf16)
    k_conv3x3_mfma<<<dim3(1024, 2), 256, 0, stream>>>(xp, wpk, pb1c, feat1);
    // 2) 1x1 conv -> feat2 (channel-last bf16)
    k_conv1x1_mfma<<<dim3(512), 256, 0, stream>>>(feat1, pw2b, pb2c, feat2);
    // 3) bilinear sample + coords -> X0 [p][v][128] bf16
    k_sample<<<dim3(NP), 128, 0, stream>>>(feat2, ipoly, cpoly, ind, X0);

    // 4) head conv -> states[0]
    k_snake_mfma<<<dim3(NP), 256, 0, stream>>>(X0, wpk2, hb, hg, hbt, nullptr,
                                               states, 1);
    // 5..11) residual dilated convs
    const int dil[NRES] = {1, 1, 1, 2, 2, 4, 4};
    const size_t SSZ = (size_t)NP * V * 128;   // elements per state
    for (int i = 0; i < NRES; ++i) {
        const __hip_bfloat16* xin = states + (size_t)i * SSZ;
        __hip_bfloat16* yout      = states + (size_t)(i + 1) * SSZ;
        const __hip_bfloat16* wi  = wpk2 + (size_t)(i + 1) * 9 * 128 * 128;
        k_snake_mfma<<<dim3(NP), 256, 0, stream>>>(xin, wi, rb + i * SD, rg + i * SD,
                                                   rbt + i * SD, xin, yout, dil[i]);
    }

    // 12) fused 1x1 over concat states -> fused [p][v][256]
    k_vconv1024<<<dim3(NP, 2), 256, 0, stream>>>(states, fwb, fb, nullptr, 0, fused);
    // 13) g = max over vertices
    k_gmax<<<dim3(NP), 256, 0, stream>>>(fused, gbuf);
    // 14) gc = pb1 + pw1[:, :256] @ g
    k_gc<<<dim3(NP), 256, 0, stream>>>(gbuf, ppw1, ppb1, gcbuf);
    // 15) h1 = relu(pw1[:, 256:] @ state + gc)
    k_vconv1024<<<dim3(NP, 2), 256, 0, stream>>>(states, pw1hb, nullptr, gcbuf, 1, h1);
    // 16) h2 = relu(pw2 @ h1 + pb2)
    k_h2<<<dim3(NP), 128, 0, stream>>>(h1, pw2b, ppb2, h2);
    // 17) final
    k_final<<<dim3(NP), 128, 0, stream>>>(h2, ppw3, ppb3, ipoly, outp);
}

// Round 4
// 497.233 us; speedup vs baseline: 5.1706x; 1.1874x over previous
//
#include <hip/hip_runtime.h>
#include <hip/hip_bf16.h>

// ---- problem constants ----
constexpr int B   = 8;
constexpr int CIN = 66;
constexpr int H   = 128, W = 128;
constexpr int C1  = 256;
constexpr int NP  = 128;
constexpr int V   = 128;
constexpr int SD  = 128;
constexpr int NRES = 7;
constexpr float RO = 4.0f;

typedef __bf16 bf16x8 __attribute__((ext_vector_type(8)));
typedef float  f32x4  __attribute__((ext_vector_type(4)));
typedef unsigned short u16x8 __attribute__((ext_vector_type(8)));

__device__ inline float bfu2f(unsigned short u) {
    union { unsigned int i; float f; } c; c.i = ((unsigned)u) << 16; return c.f;
}

// ===================== K0a: pack x -> channel-last bf16 with borders =====================
__global__ __launch_bounds__(256) void k_pack_x(const float* __restrict__ x,
                                                __hip_bfloat16* __restrict__ xp)
{
    const int bi  = blockIdx.x;          // 8*130
    const int b   = bi / 130;
    const int yp  = bi % 130;
    const int tid = threadIdx.x;
    const int y   = yp - 1;
    const bool interior = (y >= 0 && y < H);

    __shared__ float xs[CIN * W];
    if (interior) {
        for (int i = tid; i < CIN * W; i += 256)
            xs[i] = x[((size_t)b * CIN + (i >> 7)) * (H * W) + y * W + (i & 127)];
    }
    __syncthreads();
    __hip_bfloat16* op = xp + ((size_t)b * 130 + yp) * (130 * 72);
    for (int i = tid; i < 130 * 72; i += 256) {
        int xpx = i / 72, c = i - xpx * 72;
        int xx = xpx - 1;
        float v = 0.f;
        if (interior && xx >= 0 && xx < W && c < CIN) v = xs[c * W + xx];
        op[i] = __float2bfloat16(v);
    }
}

// ===================== K0b: pack w -> [3 ky][256 oc][232] bf16 =====================
__global__ __launch_bounds__(256) void k_pack_w(const float* __restrict__ w,
                                                __hip_bfloat16* __restrict__ wp)
{
    const int oc  = blockIdx.x;
    const int tid = threadIdx.x;
    for (int t = tid; t < 3 * 232; t += 256) {
        int ky = t / 232, s = t - ky * 232;
        float v = 0.f;
        if (s < 216) {
            int kx = s / 72, ic = s - kx * 72;
            if (ic < CIN) v = w[((size_t)(oc * CIN + ic) * 3 + ky) * 3 + kx];
        }
        wp[((size_t)ky * 256 + oc) * 232 + s] = __float2bfloat16(v);
    }
}

// ===================== K0c: pack snake weights -> [8][9][128 oc][128 ic] bf16 =====================
__global__ __launch_bounds__(256) void k_pack_snake_w(const float* __restrict__ hw,
                                                      const float* __restrict__ rw,
                                                      __hip_bfloat16* __restrict__ wpk2)
{
    const int l  = blockIdx.x >> 7;
    const int oc = blockIdx.x & 127;
    const int tid = threadIdx.x;
    for (int t = tid; t < 9 * 128; t += 256) {
        int k = t >> 7, ic = t & 127;
        float v = 0.f;
        if (l == 0) {
            if (ic < 66) v = hw[((size_t)oc * 66 + ic) * 9 + k];
        } else {
            v = rw[((((size_t)(l - 1) * 128 + oc) * 128) + ic) * 9 + k];
        }
        wpk2[(((size_t)l * 9 + k) * 128 + oc) * 128 + ic] = __float2bfloat16(v);
    }
}

// ===================== K0d: generic f32 matrix -> bf16 pack =====================
__global__ __launch_bounds__(256) void k_pack_mat(const float* __restrict__ src,
                                                  __hip_bfloat16* __restrict__ dst,
                                                  int rows, int cols, int rstride, int coff)
{
    int n = rows * cols;
    for (int i = blockIdx.x * 256 + threadIdx.x; i < n; i += gridDim.x * 256) {
        int r = i / cols, c = i - r * cols;
        dst[i] = __float2bfloat16(src[(size_t)r * rstride + coff + c]);
    }
}

// ===================== K1: 3x3 conv via implicit-GEMM MFMA =====================
// grid (1024 = b*128+y, 2 ocg), block 256 = 4 waves (2M x 2N), wave 64 pos x 64 oc.
// A: 3 padded input rows staged ONCE (contiguous 56160 B). B: direct global (L2-hot).
// Zero barriers in the K-loop; B K-pad slots (216..231) are zero so A overreads are harmless.
__global__ __launch_bounds__(256, 2) void k_conv3x3_mfma(
    const __hip_bfloat16* __restrict__ xp,   // [8][130][130][72]
    const __hip_bfloat16* __restrict__ wp,   // [3][256][232]
    const float* __restrict__ bias,
    __hip_bfloat16* __restrict__ out)        // [8][128 y][128 x][256 oc]
{
    __shared__ __hip_bfloat16 ash[3 * 9360 + 16];

    const int tid = threadIdx.x;
    const int ln  = tid & 63;
    const int wv  = tid >> 6;
    const int wm  = (wv >> 1) * 64;
    const int wn  = (wv & 1) * 64;
    const int l15 = ln & 15;
    const int lhi = ln >> 4;

    const int by  = blockIdx.x;
    const int b   = by >> 7;
    const int y   = by & 127;
    const int ocb = blockIdx.y * 128;

    // stage 3 padded rows (y..y+2 in padded coords) = 56160 contiguous bytes
    {
        const char* g = (const char*)(xp + ((size_t)b * 130 + y) * 9360);
        for (int off = tid * 16; off < 56160; off += 4096)
            __builtin_amdgcn_global_load_lds(
                (const __attribute__((address_space(1))) void*)(g + off),
                (__attribute__((address_space(3))) void*)((char*)ash + off),
                16, 0, 0);
    }
    __syncthreads();

    f32x4 acc[4][4] = {};
#pragma unroll 1
    for (int ky = 0; ky < 3; ++ky) {
        const __hip_bfloat16* wk = wp + ((size_t)ky * 256 + ocb) * 232;
        const char* arow = (const char*)ash + ky * 18720;
#pragma unroll
        for (int ks = 0; ks < 7; ++ks) {
            bf16x8 a[4], bq[4];
#pragma unroll
            for (int m = 0; m < 4; ++m)
                a[m] = *(const bf16x8*)(arow + (wm + m * 16 + l15) * 144 + ks * 64 + lhi * 16);
#pragma unroll
            for (int n = 0; n < 4; ++n)
                bq[n] = *(const bf16x8*)(wk + (size_t)(wn + n * 16 + l15) * 232 + ks * 32 + lhi * 8);
#pragma unroll
            for (int m = 0; m < 4; ++m)
#pragma unroll
                for (int n = 0; n < 4; ++n)
                    acc[m][n] = __builtin_amdgcn_mfma_f32_16x16x32_bf16(
                        a[m], bq[n], acc[m][n], 0, 0, 0);
        }
    }

    // epilogue: bias + relu -> channel-last bf16
#pragma unroll
    for (int n = 0; n < 4; ++n) {
        int oc = ocb + wn + n * 16 + l15;
        float bb = bias[oc];
#pragma unroll
        for (int m = 0; m < 4; ++m) {
#pragma unroll
            for (int r = 0; r < 4; ++r) {
                int pos = wm + m * 16 + lhi * 4 + r;
                float v = acc[m][n][r] + bb;
                v = v > 0.f ? v : 0.f;
                out[(((size_t)b * 128 + y) * 128 + pos) * 256 + oc] = __float2bfloat16(v);
            }
        }
    }
}

// ===================== K2: 1x1 conv (256 -> 64) MFMA =====================
__global__ __launch_bounds__(256) void k_conv1x1_mfma(
    const __hip_bfloat16* __restrict__ feat1,   // [131072 pos][256]
    const __hip_bfloat16* __restrict__ w2b,     // [64][256]
    const float* __restrict__ b2,
    __hip_bfloat16* __restrict__ feat2)         // [131072 pos][64]
{
    const int tid = threadIdx.x;
    const int ln  = tid & 63;
    const int wv  = tid >> 6;
    const int wm  = wv * 64;
    const int l15 = ln & 15;
    const int lhi = ln >> 4;
    const int pos0 = blockIdx.x * 256;

    __shared__ __hip_bfloat16 wsh[64 * 136];
    for (int i = tid; i < 1024; i += 256) {
        int row = i >> 4, slot = i & 15;
        *(bf16x8*)&wsh[row * 136 + slot * 8] = *(const bf16x8*)(w2b + row * 256 + slot * 8);
    }
    __syncthreads();

    f32x4 acc[4][4] = {};
#pragma unroll
    for (int kk = 0; kk < 8; ++kk) {
        bf16x8 a[4], bq[4];
#pragma unroll
        for (int m = 0; m < 4; ++m)
            a[m] = *(const bf16x8*)(feat1 + (size_t)(pos0 + wm + m * 16 + l15) * 256 + kk * 32 + lhi * 8);
#pragma unroll
        for (int n = 0; n < 4; ++n)
            bq[n] = *(const bf16x8*)&wsh[(n * 16 + l15) * 136 + kk * 32 + lhi * 8];
#pragma unroll
        for (int m = 0; m < 4; ++m)
#pragma unroll
            for (int n = 0; n < 4; ++n)
                acc[m][n] = __builtin_amdgcn_mfma_f32_16x16x32_bf16(a[m], bq[n], acc[m][n], 0, 0, 0);
    }
#pragma unroll
    for (int n = 0; n < 4; ++n) {
        int og = n * 16 + l15;
        float bb = b2[og];
#pragma unroll
        for (int m = 0; m < 4; ++m)
#pragma unroll
            for (int r = 0; r < 4; ++r) {
                int pos = pos0 + wm + m * 16 + lhi * 4 + r;
                feat2[(size_t)pos * 64 + og] = __float2bfloat16(acc[m][n][r] + bb);
            }
    }
}

// ===================== K3: bilinear sample + coords -> X0 [p][v][128] bf16 =====================
// 256 thr: v = tid&127, half = tid>>7 (ch groups 0-3 / 4-7); half1 writes coords+zeros
__global__ __launch_bounds__(256) void k_sample(
    const __hip_bfloat16* __restrict__ feat2, const float* __restrict__ ipoly,
    const float* __restrict__ cpoly, const int* __restrict__ ind,
    __hip_bfloat16* __restrict__ X0)
{
    const int p = blockIdx.x;
    const int v = threadIdx.x & 127;
    const int half = threadIdx.x >> 7;

    float px = ipoly[(p * V + v) * 2 + 0];
    float py = ipoly[(p * V + v) * 2 + 1];
    float ix = px - 0.5f, iy = py - 0.5f;
    float x0f = floorf(ix), y0f = floorf(iy);
    float wx = ix - x0f, wy = iy - y0f;
    int x0 = (int)x0f, y0 = (int)y0f;

    int   xsv[2] = {x0, x0 + 1}, ysv[2] = {y0, y0 + 1};
    float wxs[2] = {1.f - wx, wx}, wys[2] = {1.f - wy, wy};
    float cw[4]; int cbase[4];
#pragma unroll
    for (int jy = 0; jy < 2; ++jy)
#pragma unroll
        for (int jx = 0; jx < 2; ++jx) {
            int xi = xsv[jx], yi = ysv[jy];
            bool ok = (xi >= 0) && (xi < W) && (yi >= 0) && (yi < H);
            int xc = min(max(xi, 0), W - 1);
            int yc = min(max(yi, 0), H - 1);
            cw[jy * 2 + jx]    = wys[jy] * wxs[jx] * (ok ? 1.f : 0.f);
            cbase[jy * 2 + jx] = yc * W + xc;
        }

    const __hip_bfloat16* fb = feat2 + (size_t)ind[p] * (16384 * 64);
    __hip_bfloat16* xr = X0 + ((size_t)p * V + v) * 128;
#pragma unroll
    for (int ch = 0; ch < 4; ++ch) {
        int chh = half * 4 + ch;
        float s[8];
#pragma unroll
        for (int e = 0; e < 8; ++e) s[e] = 0.f;
#pragma unroll
        for (int j = 0; j < 4; ++j) {
            u16x8 t = *(const u16x8*)(fb + (size_t)cbase[j] * 64 + chh * 8);
#pragma unroll
            for (int e = 0; e < 8; ++e) s[e] += cw[j] * bfu2f(t[e]);
        }
#pragma unroll
        for (int e = 0; e < 8; ++e) xr[chh * 8 + e] = __float2bfloat16(s[e]);
    }
    if (half) {
        xr[64] = __float2bfloat16(cpoly[(p * V + v) * 2 + 0] * RO);
        xr[65] = __float2bfloat16(cpoly[(p * V + v) * 2 + 1] * RO);
        for (int c = 66; c < 128; ++c) xr[c] = __float2bfloat16(0.f);
    }
}

// ===================== K4: snake circular conv layer (MFMA) =====================
// grid (NP, 2 ocg), 256 thr = 4 waves 2x2, wave 64 pos x 32 oc.
// x staged once in LDS [128 v][136]; weights direct from global (L2-hot).
__global__ __launch_bounds__(256) void k_snake_mfma(
    const __hip_bfloat16* __restrict__ xin,   // [NP][V][128]
    const __hip_bfloat16* __restrict__ wl,    // [9][128 oc][128 ic]
    const float* __restrict__ bias, const float* __restrict__ gamma,
    const float* __restrict__ beta,
    const __hip_bfloat16* __restrict__ resin, // nullable, [NP][V][128]
    __hip_bfloat16* __restrict__ out,         // [NP][V][128]
    int dil)
{
    const int tid = threadIdx.x;
    const int ln  = tid & 63;
    const int wv  = tid >> 6;
    const int wm  = (wv >> 1) * 64;
    const int wn  = (wv & 1) * 32;
    const int l15 = ln & 15;
    const int lhi = ln >> 4;
    const int p   = blockIdx.x;
    const int ocb = blockIdx.y * 64;

    __shared__ __hip_bfloat16 xs[128 * 136];
    const __hip_bfloat16* xb = xin + (size_t)p * (V * 128);
    for (int i = tid; i < 2048; i += 256) {
        int v = i >> 4, slot = i & 15;
        *(bf16x8*)&xs[v * 136 + slot * 8] = *(const bf16x8*)(xb + v * 128 + slot * 8);
    }
    __syncthreads();

    f32x4 acc[4][2] = {};
#pragma unroll 1
    for (int k = 0; k < 9; ++k) {
        const int shift = (k - 4) * dil + 256;  // keep positive before &127
        const __hip_bfloat16* wk = wl + (size_t)k * (128 * 128);
#pragma unroll
        for (int kc = 0; kc < 4; ++kc) {
            bf16x8 a[4], bq[2];
#pragma unroll
            for (int m = 0; m < 4; ++m) {
                int row = (wm + m * 16 + l15 + shift) & 127;
                a[m] = *(const bf16x8*)&xs[row * 136 + kc * 32 + lhi * 8];
            }
#pragma unroll
            for (int n = 0; n < 2; ++n)
                bq[n] = *(const bf16x8*)(wk + (size_t)(ocb + wn + n * 16 + l15) * 128 + kc * 32 + lhi * 8);
#pragma unroll
            for (int m = 0; m < 4; ++m)
#pragma unroll
                for (int n = 0; n < 2; ++n)
                    acc[m][n] = __builtin_amdgcn_mfma_f32_16x16x32_bf16(a[m], bq[n], acc[m][n], 0, 0, 0);
        }
    }

#pragma unroll
    for (int n = 0; n < 2; ++n) {
        int oc = ocb + wn + n * 16 + l15;
        float bb = bias[oc], gg = gamma[oc], bt = beta[oc];
#pragma unroll
        for (int m = 0; m < 4; ++m)
#pragma unroll
            for (int r = 0; r < 4; ++r) {
                int pos = wm + m * 16 + lhi * 4 + r;
                size_t idx = ((size_t)p * V + pos) * 128 + oc;
                float v = acc[m][n][r] + bb;
                v = v > 0.f ? v : 0.f;
                v = v * gg + bt;
                if (resin) v += __bfloat162float(resin[idx]);
                out[idx] = __float2bfloat16(v);
            }
    }
}

// ===================== K5: vconv over concat states (K=1024, O=256) =====================
__global__ __launch_bounds__(256) void k_vconv1024(
    const __hip_bfloat16* __restrict__ xin,   // states [8][NP][V][128]
    const __hip_bfloat16* __restrict__ wb,    // [256][1024]
    const float* __restrict__ fbias,          // nullable [256]
    const float* __restrict__ pbias,          // nullable [NP][256]
    int relu,
    __hip_bfloat16* __restrict__ out)         // [NP][V][256]
{
    const int tid = threadIdx.x;
    const int ln  = tid & 63;
    const int wv  = tid >> 6;
    const int wm  = (wv >> 1) * 64;
    const int wn  = (wv & 1) * 64;
    const int l15 = ln & 15;
    const int lhi = ln >> 4;
    const int p   = blockIdx.x;
    const int ocb = blockIdx.y * 128;

    f32x4 acc[4][4] = {};
    for (int s = 0; s < 8; ++s) {
        const __hip_bfloat16* xa = xin + ((size_t)s * NP + p) * (V * 128);
#pragma unroll
        for (int kc = 0; kc < 4; ++kc) {
            bf16x8 a[4], bq[4];
#pragma unroll
            for (int m = 0; m < 4; ++m)
                a[m] = *(const bf16x8*)(xa + (size_t)(wm + m * 16 + l15) * 128 + kc * 32 + lhi * 8);
#pragma unroll
            for (int n = 0; n < 4; ++n)
                bq[n] = *(const bf16x8*)(wb + (size_t)(ocb + wn + n * 16 + l15) * 1024 + s * 128 + kc * 32 + lhi * 8);
#pragma unroll
            for (int m = 0; m < 4; ++m)
#pragma unroll
                for (int n = 0; n < 4; ++n)
                    acc[m][n] = __builtin_amdgcn_mfma_f32_16x16x32_bf16(a[m], bq[n], acc[m][n], 0, 0, 0);
        }
    }
#pragma unroll
    for (int n = 0; n < 4; ++n) {
        int og = ocb + wn + n * 16 + l15;
        float bb = (fbias ? fbias[og] : 0.f) + (pbias ? pbias[(size_t)p * 256 + og] : 0.f);
#pragma unroll
        for (int m = 0; m < 4; ++m)
#pragma unroll
            for (int r = 0; r < 4; ++r) {
                int pos = wm + m * 16 + lhi * 4 + r;
                float v = acc[m][n][r] + bb;
                if (relu) v = v > 0.f ? v : 0.f;
                out[((size_t)p * V + pos) * 256 + og] = __float2bfloat16(v);
            }
    }
}

// ===================== K6: h2 = relu(pw2 @ h1 + pb2)  (K=256, O=64) =====================
__global__ __launch_bounds__(128) void k_h2(
    const __hip_bfloat16* __restrict__ h1,    // [NP][V][256]
    const __hip_bfloat16* __restrict__ w2b,   // [64][256]
    const float* __restrict__ pb2,
    __hip_bfloat16* __restrict__ h2)          // [NP][V][64]
{
    const int tid = threadIdx.x;
    const int ln  = tid & 63;
    const int wv  = tid >> 6;
    const int wm  = wv * 64;
    const int l15 = ln & 15;
    const int lhi = ln >> 4;
    const int p   = blockIdx.x;

    f32x4 acc[4][4] = {};
#pragma unroll
    for (int kk = 0; kk < 8; ++kk) {
        bf16x8 a[4], bq[4];
#pragma unroll
        for (int m = 0; m < 4; ++m)
            a[m] = *(const bf16x8*)(h1 + ((size_t)p * V + wm + m * 16 + l15) * 256 + kk * 32 + lhi * 8);
#pragma unroll
        for (int n = 0; n < 4; ++n)
            bq[n] = *(const bf16x8*)(w2b + (size_t)(n * 16 + l15) * 256 + kk * 32 + lhi * 8);
#pragma unroll
        for (int m = 0; m < 4; ++m)
#pragma unroll
            for (int n = 0; n < 4; ++n)
                acc[m][n] = __builtin_amdgcn_mfma_f32_16x16x32_bf16(a[m], bq[n], acc[m][n], 0, 0, 0);
    }
#pragma unroll
    for (int n = 0; n < 4; ++n) {
        int og = n * 16 + l15;
        float bb = pb2[og];
#pragma unroll
        for (int m = 0; m < 4; ++m)
#pragma unroll
            for (int r = 0; r < 4; ++r) {
                int pos = wm + m * 16 + lhi * 4 + r;
                float v = acc[m][n][r] + bb;
                v = v > 0.f ? v : 0.f;
                h2[((size_t)p * V + pos) * 64 + og] = __float2bfloat16(v);
            }
    }
}

// ===================== K7: max over vertices (fused [p][v][256] bf16) =====================
__global__ __launch_bounds__(256) void k_gmax(const __hip_bfloat16* __restrict__ fused,
                                              float* __restrict__ g)
{
    int p = blockIdx.x, o = threadIdx.x;
    float m = -3.4e38f;
    for (int v = 0; v < V; ++v)
        m = fmaxf(m, __bfloat162float(fused[((size_t)p * V + v) * 256 + o]));
    g[(size_t)p * 256 + o] = m;
}

// ===================== K8: gc[p][o] = pb1[o] + pw1[o,0:256] . g[p] =====================
__global__ __launch_bounds__(256) void k_gc(const float* __restrict__ g,
                                            const float* __restrict__ pw1,
                                            const float* __restrict__ pb1,
                                            float* __restrict__ gc)
{
    int p = blockIdx.x, o = threadIdx.x;
    __shared__ float gl[256];
    gl[o] = g[(size_t)p * 256 + o];
    __syncthreads();
    float a = pb1[o];
    const float* wr = pw1 + (size_t)o * 1280;
    for (int c = 0; c < 256; ++c) a += wr[c] * gl[c];
    gc[(size_t)p * 256 + o] = a;
}

// ===================== K9: final pw3 + compose output =====================
__global__ __launch_bounds__(128) void k_final(const __hip_bfloat16* __restrict__ h2,
                                               const float* __restrict__ pw3,
                                               const float* __restrict__ pb3,
                                               const float* __restrict__ ipoly,
                                               float* __restrict__ outp)
{
    int p = blockIdx.x, v = threadIdx.x;
    __shared__ float w3[128];
    w3[v] = pw3[v];
    __syncthreads();
    float a0 = pb3[0], a1 = pb3[1];
    const u16x8* hp = (const u16x8*)(h2 + ((size_t)p * V + v) * 64);
#pragma unroll
    for (int ch = 0; ch < 8; ++ch) {
        u16x8 t = hp[ch];
#pragma unroll
        for (int e = 0; e < 8; ++e) {
            int c = ch * 8 + e;
            float hv = bfu2f(t[e]);
            a0 += w3[c] * hv;
            a1 += w3[64 + c] * hv;
        }
    }
    int idx = (p * V + v) * 2;
    outp[idx]     = ipoly[idx] * RO + a0;
    outp[idx + 1] = ipoly[idx + 1] * RO + a1;
}

// ===================== host =====================
extern "C" void kernel_launch(void* const* d_in, const int* in_sizes, int n_in,
                              void* d_out, int out_size, void* d_ws, size_t ws_size,
                              hipStream_t stream)
{
    const float* cnn   = (const float*)d_in[0];
    const float* ipoly = (const float*)d_in[1];
    const float* cpoly = (const float*)d_in[2];
    const int*   ind   = (const int*)d_in[3];
    const float* pw1c  = (const float*)d_in[4];
    const float* pb1c  = (const float*)d_in[5];
    const float* pw2c  = (const float*)d_in[6];
    const float* pb2c  = (const float*)d_in[7];
    const float* hw    = (const float*)d_in[8];
    const float* hb    = (const float*)d_in[9];
    const float* hg    = (const float*)d_in[10];
    const float* hbt   = (const float*)d_in[11];
    const float* rw    = (const float*)d_in[12];
    const float* rb    = (const float*)d_in[13];
    const float* rg    = (const float*)d_in[14];
    const float* rbt   = (const float*)d_in[15];
    const float* fw    = (const float*)d_in[16];
    const float* fb    = (const float*)d_in[17];
    const float* ppw1  = (const float*)d_in[18];
    const float* ppb1  = (const float*)d_in[19];
    const float* ppw2  = (const float*)d_in[20];
    const float* ppb2  = (const float*)d_in[21];
    const float* ppw3  = (const float*)d_in[22];
    const float* ppb3  = (const float*)d_in[23];
    float* outp = (float*)d_out;

    char* ws = (char*)d_ws;
    __hip_bfloat16* feat1  = (__hip_bfloat16*)(ws);
    __hip_bfloat16* states = (__hip_bfloat16*)(ws);
    __hip_bfloat16* fused  = (__hip_bfloat16*)(ws + 33554432);
    __hip_bfloat16* h1     = (__hip_bfloat16*)(ws + 41943040);
    __hip_bfloat16* h2     = (__hip_bfloat16*)(ws + 50331648);
    float*          gbuf   = (float*)(ws + 52428800);
    float*          gcbuf  = (float*)(ws + 52559872);
    __hip_bfloat16* xp     = (__hip_bfloat16*)(ws + 67108864);
    __hip_bfloat16* feat2  = (__hip_bfloat16*)(ws + 67108864);
    __hip_bfloat16* wpk    = (__hip_bfloat16*)(ws + 86577664);
    __hip_bfloat16* wpk2   = (__hip_bfloat16*)(ws + 87023104);
    __hip_bfloat16* fwb    = (__hip_bfloat16*)(ws + 89382400);
    __hip_bfloat16* pw1hb  = (__hip_bfloat16*)(ws + 89906688);
    __hip_bfloat16* pw2b   = (__hip_bfloat16*)(ws + 90430976);
    __hip_bfloat16* X0     = (__hip_bfloat16*)(ws + 90472448);

    // 0) packs
    k_pack_x<<<dim3(8 * 130), 256, 0, stream>>>(cnn, xp);
    k_pack_w<<<dim3(256), 256, 0, stream>>>(pw1c, wpk);
    k_pack_snake_w<<<dim3(8 * 128), 256, 0, stream>>>(hw, rw, wpk2);
    k_pack_mat<<<dim3(256), 256, 0, stream>>>(fw, fwb, 256, 1024, 1024, 0);
    k_pack_mat<<<dim3(256), 256, 0, stream>>>(ppw1, pw1hb, 256, 1024, 1280, 256);
    k_pack_mat<<<dim3(64), 256, 0, stream>>>(ppw2, pw2b, 64, 256, 256, 0);

    // 1) 3x3 conv + relu -> feat1 (channel-last bf16)
    k_conv3x3_mfma<<<dim3(1024, 2), 256, 0, stream>>>(xp, wpk, pb1c, feat1);
    // 2) 1x1 conv -> feat2 (channel-last bf16)
    k_conv1x1_mfma<<<dim3(512), 256, 0, stream>>>(feat1, pw2b, pb2c, feat2);
    // 3) bilinear sample + coords -> X0 [p][v][128] bf16
    k_sample<<<dim3(NP), 256, 0, stream>>>(feat2, ipoly, cpoly, ind, X0);

    // 4) head conv -> states[0]
    k_snake_mfma<<<dim3(NP, 2), 256, 0, stream>>>(X0, wpk2, hb, hg, hbt, nullptr,
                                                  states, 1);
    // 5..11) residual dilated convs
    const int dil[NRES] = {1, 1, 1, 2, 2, 4, 4};
    const size_t SSZ = (size_t)NP * V * 128;
    for (int i = 0; i < NRES; ++i) {
        const __hip_bfloat16* xin = states + (size_t)i * SSZ;
        __hip_bfloat16* yout      = states + (size_t)(i + 1) * SSZ;
        const __hip_bfloat16* wi  = wpk2 + (size_t)(i + 1) * 9 * 128 * 128;
        k_snake_mfma<<<dim3(NP, 2), 256, 0, stream>>>(xin, wi, rb + i * SD, rg + i * SD,
                                                      rbt + i * SD, xin, yout, dil[i]);
    }

    // 12) fused 1x1 over concat states -> fused [p][v][256]
    k_vconv1024<<<dim3(NP, 2), 256, 0, stream>>>(states, fwb, fb, nullptr, 0, fused);
    // 13) g = max over vertices
    k_gmax<<<dim3(NP), 256, 0, stream>>>(fused, gbuf);
    // 14) gc = pb1 + pw1[:, :256] @ g
    k_gc<<<dim3(NP), 256, 0, stream>>>(gbuf, ppw1, ppb1, gcbuf);
    // 15) h1 = relu(pw1[:, 256:] @ state + gc)
    k_vconv1024<<<dim3(NP, 2), 256, 0, stream>>>(states, pw1hb, nullptr, gcbuf, 1, h1);
    // 16) h2 = relu(pw2 @ h1 + pb2)
    k_h2<<<dim3(NP), 128, 0, stream>>>(h1, pw2b, ppb2, h2);
    // 17) final
    k_final<<<dim3(NP), 128, 0, stream>>>(h2, ppw3, ppb3, ipoly, outp);
}